// Round 6
// baseline (725.105 us; speedup 1.0000x reference)
//
#include <hip/hip_runtime.h>
#include <math.h>

#define N_ 2048
#define NF_IN 64
#define D_ 256
#define H_ 8
#define HD_ 32
#define L_ 6
#define FFN_ 1024
#define E_ 32768
#define EF_ 16
#define NF 2049      // N+1 tokens (CLS at row 0)
#define MAXDEG_ 64
#define BSTRIDE 2112 // padded row stride: bytes for fp8 bias, shorts for Vt
#define RPAD 2112    // padded row count for attention partials
#define NSPLIT 4     // key splits for flash attention
#define LOG2E 1.4426950408889634f

typedef __attribute__((ext_vector_type(8))) short bf16x8;
typedef __attribute__((ext_vector_type(4))) float f32x4;

__device__ inline unsigned short f2b(float f){
  union { float f; unsigned u; } v; v.f = f;
  unsigned r = (v.u + 0x7fffu + ((v.u >> 16) & 1u)) >> 16;
  return (unsigned short)r;
}
__device__ inline float b2f(short s){
  union { unsigned u; float f; } v; v.u = ((unsigned)(unsigned short)s) << 16;
  return v.f;
}

// manual OCP e4m3fn encode, RNE (prep-path only)
__device__ inline unsigned char f2fp8(float f){
  unsigned u = __float_as_uint(f);
  unsigned s = (u >> 24) & 0x80u;
  float a = fabsf(f);
  if (a >= 448.f) return (unsigned char)(s | 0x7Eu);
  if (a < 0.015625f){                      // denormal region (incl. 0)
    int k = (int)rintf(a * 512.f);         // step 2^-9; k=8 rolls into 2^-6
    return (unsigned char)(s | (unsigned)k);
  }
  int e; float m = frexpf(a, &e);          // a = m*2^e, m in [0.5,1)
  int E = e - 1;
  int m3 = (int)rintf(m * 16.f) - 8;       // 0..8
  if (m3 == 8){ E++; m3 = 0; }
  if (E > 8){ E = 8; m3 = 6; }
  if (E == 8 && m3 > 6) m3 = 6;
  return (unsigned char)(s | (unsigned)((E + 7) << 3) | (unsigned)m3);
}
__device__ inline float fp82f(unsigned char b){
  return __builtin_amdgcn_cvt_f32_fp8((int)b, 0);
}

__device__ inline void atomic_add_fp8(unsigned char* p, float add){
  unsigned* wp = (unsigned*)((size_t)p & ~(size_t)3);
  int sh = (int)((size_t)p & 3) * 8;
  unsigned old = *wp, assumed;
  do {
    assumed = old;
    unsigned char cur = (unsigned char)((assumed >> sh) & 0xFFu);
    float f = fp82f(cur) + add;
    unsigned nw = (assumed & ~(0xFFu << sh)) | ((unsigned)f2fp8(f) << sh);
    old = atomicCAS(wp, assumed, nw);
  } while (old != assumed);
}

__global__ void zero_int(int* p, int n){
  int i = blockIdx.x * blockDim.x + threadIdx.x;
  if (i < n) p[i] = 0;
}

__global__ void deg_count(const int* __restrict__ ei, int* __restrict__ ind,
                          int* __restrict__ outd){
  int e = blockIdx.x * blockDim.x + threadIdx.x;
  if (e >= E_) return;
  atomicAdd(&outd[ei[e]], 1);
  atomicAdd(&ind[ei[E_ + e]], 1);
}

__global__ void embed_k(const float* __restrict__ x, const float* __restrict__ W,
                        const float* __restrict__ b, const float* __restrict__ inE,
                        const float* __restrict__ outE, const int* __restrict__ ind,
                        const int* __restrict__ outd, const float* __restrict__ cls,
                        float* __restrict__ h){
  int i = blockIdx.x, d = threadIdx.x;
  if (i == 0){ h[d] = cls[d]; return; }
  int n = i - 1;
  const float4* xr = (const float4*)(x + (long)n * NF_IN);
  const float4* wr = (const float4*)(W + (long)d * NF_IN);
  float acc = b[d];
  #pragma unroll
  for (int k = 0; k < NF_IN / 4; k++){
    float4 a = xr[k], w = wr[k];
    acc += a.x * w.x + a.y * w.y + a.z * w.z + a.w * w.w;
  }
  int id = min(ind[n], MAXDEG_), od = min(outd[n], MAXDEG_);
  acc += inE[(long)id * D_ + d] + outE[(long)od * D_ + d];
  h[(long)i * D_ + d] = acc;
}

// bias stored as fp8 of (bias * log2e) — exp2-domain; grid NF
__global__ void bias_fill(const int* __restrict__ dist, const float* __restrict__ db,
                          unsigned char* __restrict__ bb){
  __shared__ unsigned char lut8[10][H_];
  int i = blockIdx.x;
  if (threadIdx.x < 80)
    ((unsigned char*)lut8)[threadIdx.x] = f2fp8(db[threadIdx.x] * LOG2E);
  __syncthreads();
  for (int u = threadIdx.x; u < BSTRIDE / 8; u += 256){
    int dp[8];
    #pragma unroll
    for (int k = 0; k < 8; k++){
      int j = u * 8 + k;
      int d = 0;
      if (i > 0 && j > 0 && j < NF){
        int dv = dist[(long)(i - 1) * N_ + (j - 1)];
        d = max(0, min(dv, 9));
      }
      dp[k] = (j < NF) ? d : -1;
    }
    #pragma unroll
    for (int h = 0; h < H_; h++){
      unsigned lo = 0, hi = 0;
      #pragma unroll
      for (int k = 0; k < 4; k++){
        unsigned b0 = (dp[k] >= 0) ? lut8[dp[k]][h] : 0u;
        unsigned b1 = (dp[4 + k] >= 0) ? lut8[dp[4 + k]][h] : 0u;
        lo |= b0 << (8 * k);
        hi |= b1 << (8 * k);
      }
      *(uint2*)(bb + ((long)h * NF + i) * BSTRIDE + u * 8) = make_uint2(lo, hi);
    }
  }
}

// sparse edge-feature bias: byte-CAS fp8 add (also log2e-scaled)
__global__ void edge_bias(const float* __restrict__ ea, const float* __restrict__ W,
                          const float* __restrict__ b, const int* __restrict__ ei,
                          unsigned char* __restrict__ bb){
  int e = blockIdx.x * blockDim.x + threadIdx.x;
  if (e >= E_) return;
  float a[EF_];
  #pragma unroll
  for (int k = 0; k < EF_; k++) a[k] = ea[(long)e * EF_ + k];
  int src = ei[e], dst = ei[E_ + e];
  #pragma unroll
  for (int h = 0; h < H_; h++){
    float p = b[h];
    #pragma unroll
    for (int k = 0; k < EF_; k++) p += a[k] * W[h * EF_ + k];
    atomic_add_fp8(bb + ((long)h * NF + src + 1) * BSTRIDE + (dst + 1), p * LOG2E);
  }
}

// all weight conversions in one dispatch
__global__ void w2b_all(const float* __restrict__ qw, const float* __restrict__ kw,
                        const float* __restrict__ vw, const float* __restrict__ ow,
                        const float* __restrict__ f1w, const float* __restrict__ f2w,
                        short* __restrict__ wqkv, short* __restrict__ owb,
                        short* __restrict__ f1wb, short* __restrict__ f2wb){
  long i = (long)blockIdx.x * 256 + threadIdx.x;
  const long DD = (long)D_ * D_, LDD = (long)L_ * DD, LFD = (long)L_ * FFN_ * D_;
  if (i < LDD){
    long l = i / DD, r = i - l * DD;
    wqkv[l * 3 * DD + r]          = (short)f2b(qw[i]);
    wqkv[l * 3 * DD + DD + r]     = (short)f2b(kw[i]);
    wqkv[l * 3 * DD + 2 * DD + r] = (short)f2b(vw[i]);
    owb[i] = (short)f2b(ow[i]);
  }
  if (i < LFD){
    f1wb[i] = (short)f2b(f1w[i]);
    f2wb[i] = (short)f2b(f2w[i]);
  }
}

// wave-per-row layernorm: 4 rows/block, no LDS, no barriers. (final LN only)
__global__ __launch_bounds__(256) void ln_k(const float* __restrict__ in,
                     const float* __restrict__ s, const float* __restrict__ b,
                     float* __restrict__ outf, short* __restrict__ outb,
                     int dup0, int M){
  int row = blockIdx.x * 4 + (threadIdx.x >> 6);
  int lane = threadIdx.x & 63;
  if (row >= M) return;
  float4 v = *(const float4*)(in + (long)row * D_ + lane * 4);
  float s1 = v.x + v.y + v.z + v.w;
  float s2 = v.x * v.x + v.y * v.y + v.z * v.z + v.w * v.w;
  #pragma unroll
  for (int o = 1; o < 64; o <<= 1){
    s1 += __shfl_xor(s1, o, 64);
    s2 += __shfl_xor(s2, o, 64);
  }
  float m = s1 * (1.0f / D_);
  float var = s2 * (1.0f / D_) - m * m;
  float rstd = rsqrtf(var + 1e-5f);
  float4 sc = *(const float4*)(s + lane * 4);
  float4 bb = *(const float4*)(b + lane * 4);
  float y0 = (v.x - m) * rstd * sc.x + bb.x;
  float y1 = (v.y - m) * rstd * sc.y + bb.y;
  float y2 = (v.z - m) * rstd * sc.z + bb.z;
  float y3 = (v.w - m) * rstd * sc.w + bb.w;
  if (outf){
    float4 o4 = make_float4(y0, y1, y2, y3);
    *(float4*)(outf + (long)row * D_ + lane * 4) = o4;
    if (dup0 && row == 0) *(float4*)(outf + (long)NF * D_ + lane * 4) = o4;
  }
  if (outb){
    short4 pk;
    pk.x = (short)f2b(y0); pk.y = (short)f2b(y1);
    pk.z = (short)f2b(y2); pk.w = (short)f2b(y3);
    *(short4*)(outb + (long)row * D_ + lane * 4) = pk;
  }
}

// ---- fused LN1 + QKV MFMA GEMM: grid (33, 4, 3).
// LN of the block's 64 A-rows is computed in the prologue (bit-identical to
// ln_k: same float4 lane layout, same shfl_xor reduce order, same f2b) into a
// fully LDS-resident post-LN A tile [64][256]. This removes the separate ln
// dispatch; LN is redundantly computed by the 12 (bn,z) blocks per bm — cheap,
// h slice is L2-resident. K-loop stages only W (double-buffered).
// z==0 (Q) pre-scaled by (1/sqrt(HD))*log2e; z==2 (V) transposes via LDS.
__global__ __launch_bounds__(256) void qkv_gemm(const float* __restrict__ hsrc,
    const float* __restrict__ lns, const float* __restrict__ lnb,
    const short* __restrict__ Wall, const float* __restrict__ qb,
    const float* __restrict__ kb, const float* __restrict__ vb,
    short* __restrict__ QKb, short* __restrict__ Vtg, int l){
  const int z = blockIdx.z;
  const short* W = Wall + ((long)(l * 3 + z)) * D_ * D_;
  const float* bsp = (z == 0) ? qb : (z == 1) ? kb : vb;
  __shared__ __align__(16) short Af[64][264];  // post-LN A tile; stride 264 -> 2-way (free)
  __shared__ __align__(16) short Ws2[2][64][40];
  __shared__ __align__(16) short Tt[64][72];   // V transpose buffer [dim][key]
  const int tid = threadIdx.x, lane = tid & 63, wave = tid >> 6;
  const int col = lane & 15, quad = lane >> 4;
  const int wm = wave & 1, wn = wave >> 1;
  const int bm = blockIdx.x * 64, bn = blockIdx.y * 64;
  const f32x4 zero4 = {0.f, 0.f, 0.f, 0.f};
  f32x4 acc[2][2] = {{zero4, zero4}, {zero4, zero4}};
  const int row = tid >> 2, seg = tid & 3;

  auto stageW = [&](int buf, int k0){
    *(bf16x8*)&Ws2[buf][row][seg * 8] =
      *(const bf16x8*)(W + (long)(bn + row) * D_ + k0 + seg * 8);
  };

  stageW(0, 0);   // issue W loads first so they fly during LN compute

  { // LN prologue: wave w computes rows w*16..w*16+15 (all 64 lanes per row)
    float4 sc4 = *(const float4*)(lns + lane * 4);
    float4 bb4 = *(const float4*)(lnb + lane * 4);
    #pragma unroll 4
    for (int r16 = 0; r16 < 16; r16++){
      int r = wave * 16 + r16;
      int gm = bm + r;
      float4 v = make_float4(0.f, 0.f, 0.f, 0.f);
      if (gm < NF) v = *(const float4*)(hsrc + (long)gm * D_ + lane * 4);
      float s1 = v.x + v.y + v.z + v.w;
      float s2 = v.x * v.x + v.y * v.y + v.z * v.z + v.w * v.w;
      #pragma unroll
      for (int o = 1; o < 64; o <<= 1){
        s1 += __shfl_xor(s1, o, 64);
        s2 += __shfl_xor(s2, o, 64);
      }
      float m = s1 * (1.0f / D_);
      float var = s2 * (1.0f / D_) - m * m;
      float rstd = rsqrtf(var + 1e-5f);
      short4 pk;
      pk.x = (short)f2b((v.x - m) * rstd * sc4.x + bb4.x);
      pk.y = (short)f2b((v.y - m) * rstd * sc4.y + bb4.y);
      pk.z = (short)f2b((v.z - m) * rstd * sc4.z + bb4.z);
      pk.w = (short)f2b((v.w - m) * rstd * sc4.w + bb4.w);
      *(short4*)&Af[r][lane * 4] = pk;  // all lanes same row: conflict-free
    }
  }

  int cur = 0;
  for (int k0 = 0; k0 < D_; k0 += 32){
    __syncthreads();
    if (k0 + 32 < D_) stageW(cur ^ 1, k0 + 32);
    bf16x8 a0 = *(const bf16x8*)&Af[wm * 32 + col][k0 + quad * 8];
    bf16x8 a1 = *(const bf16x8*)&Af[wm * 32 + 16 + col][k0 + quad * 8];
    bf16x8 b0 = *(const bf16x8*)&Ws2[cur][wn * 32 + col][quad * 8];
    bf16x8 b1 = *(const bf16x8*)&Ws2[cur][wn * 32 + 16 + col][quad * 8];
    acc[0][0] = __builtin_amdgcn_mfma_f32_16x16x32_bf16(a0, b0, acc[0][0], 0, 0, 0);
    acc[0][1] = __builtin_amdgcn_mfma_f32_16x16x32_bf16(a0, b1, acc[0][1], 0, 0, 0);
    acc[1][0] = __builtin_amdgcn_mfma_f32_16x16x32_bf16(a1, b0, acc[1][0], 0, 0, 0);
    acc[1][1] = __builtin_amdgcn_mfma_f32_16x16x32_bf16(a1, b1, acc[1][1], 0, 0, 0);
    cur ^= 1;
  }
  if (z < 2){
    const float qscale = 0.25501133194822025f;  // (1/sqrt(32)) * log2e
    #pragma unroll
    for (int i = 0; i < 2; i++)
      #pragma unroll
      for (int j = 0; j < 2; j++)
        #pragma unroll
        for (int r = 0; r < 4; r++){
          int gm = bm + wm * 32 + i * 16 + quad * 4 + r;
          if (gm >= NF) continue;
          int gn = bn + wn * 32 + j * 16 + col;
          float v = acc[i][j][r] + bsp[gn];
          if (z == 0) v *= qscale;
          QKb[(long)z * NF * D_ + (long)gm * D_ + gn] = (short)f2b(v);
        }
  } else {
    // transpose tile into LDS: Tt[dim][key]; rows gm>=NF hold finite values
    // (LN of zero row -> bias vector -> finite; masked by P=0 in fattn)
    #pragma unroll
    for (int i = 0; i < 2; i++)
      #pragma unroll
      for (int j = 0; j < 2; j++){
        int ln_ = wn * 32 + j * 16 + col;     // local dim
        int lc = wm * 32 + i * 16 + quad * 4; // local key base (4 consecutive)
        float bsv = bsp[bn + ln_];
        short pk[4];
        #pragma unroll
        for (int r = 0; r < 4; r++) pk[r] = (short)f2b(acc[i][j][r] + bsv);
        *(short4*)&Tt[ln_][lc] = *(short4*)pk;
      }
    __syncthreads();
    int lr = tid >> 2, sg = tid & 3;
    bf16x8 v0 = *(const bf16x8*)&Tt[lr][sg * 16];
    bf16x8 v1 = *(const bf16x8*)&Tt[lr][sg * 16 + 8];
    short* dstp = Vtg + (long)(bn + lr) * BSTRIDE + bm + sg * 16;
    *(bf16x8*)dstp = v0;
    *(bf16x8*)(dstp + 8) = v1;
  }
}

// ---- fused LN2 + FFN1 GEMM (+GELU): grid (33, 16). Same LN-in-prologue
// trick as qkv_gemm; K = D_ = 256, full post-LN A tile in LDS, W dbuf.
__global__ __launch_bounds__(256) void ffn1_ln(const float* __restrict__ hsrc,
    const float* __restrict__ lns, const float* __restrict__ lnb,
    const short* __restrict__ W, const float* __restrict__ bs,
    short* __restrict__ Cb){
  __shared__ __align__(16) short Af[64][264];
  __shared__ __align__(16) short Ws2[2][64][40];
  const int tid = threadIdx.x, lane = tid & 63, wave = tid >> 6;
  const int col = lane & 15, quad = lane >> 4;
  const int wm = wave & 1, wn = wave >> 1;
  const int bm = blockIdx.x * 64, bn = blockIdx.y * 64;
  const f32x4 zero4 = {0.f, 0.f, 0.f, 0.f};
  f32x4 acc[2][2] = {{zero4, zero4}, {zero4, zero4}};
  const int row = tid >> 2, seg = tid & 3;

  auto stageW = [&](int buf, int k0){
    *(bf16x8*)&Ws2[buf][row][seg * 8] =
      *(const bf16x8*)(W + (long)(bn + row) * D_ + k0 + seg * 8);
  };

  stageW(0, 0);

  {
    float4 sc4 = *(const float4*)(lns + lane * 4);
    float4 bb4 = *(const float4*)(lnb + lane * 4);
    #pragma unroll 4
    for (int r16 = 0; r16 < 16; r16++){
      int r = wave * 16 + r16;
      int gm = bm + r;
      float4 v = make_float4(0.f, 0.f, 0.f, 0.f);
      if (gm < NF) v = *(const float4*)(hsrc + (long)gm * D_ + lane * 4);
      float s1 = v.x + v.y + v.z + v.w;
      float s2 = v.x * v.x + v.y * v.y + v.z * v.z + v.w * v.w;
      #pragma unroll
      for (int o = 1; o < 64; o <<= 1){
        s1 += __shfl_xor(s1, o, 64);
        s2 += __shfl_xor(s2, o, 64);
      }
      float m = s1 * (1.0f / D_);
      float var = s2 * (1.0f / D_) - m * m;
      float rstd = rsqrtf(var + 1e-5f);
      short4 pk;
      pk.x = (short)f2b((v.x - m) * rstd * sc4.x + bb4.x);
      pk.y = (short)f2b((v.y - m) * rstd * sc4.y + bb4.y);
      pk.z = (short)f2b((v.z - m) * rstd * sc4.z + bb4.z);
      pk.w = (short)f2b((v.w - m) * rstd * sc4.w + bb4.w);
      *(short4*)&Af[r][lane * 4] = pk;
    }
  }

  int cur = 0;
  for (int k0 = 0; k0 < D_; k0 += 32){
    __syncthreads();
    if (k0 + 32 < D_) stageW(cur ^ 1, k0 + 32);
    bf16x8 a0 = *(const bf16x8*)&Af[wm * 32 + col][k0 + quad * 8];
    bf16x8 a1 = *(const bf16x8*)&Af[wm * 32 + 16 + col][k0 + quad * 8];
    bf16x8 b0 = *(const bf16x8*)&Ws2[cur][wn * 32 + col][quad * 8];
    bf16x8 b1 = *(const bf16x8*)&Ws2[cur][wn * 32 + 16 + col][quad * 8];
    acc[0][0] = __builtin_amdgcn_mfma_f32_16x16x32_bf16(a0, b0, acc[0][0], 0, 0, 0);
    acc[0][1] = __builtin_amdgcn_mfma_f32_16x16x32_bf16(a0, b1, acc[0][1], 0, 0, 0);
    acc[1][0] = __builtin_amdgcn_mfma_f32_16x16x32_bf16(a1, b0, acc[1][0], 0, 0, 0);
    acc[1][1] = __builtin_amdgcn_mfma_f32_16x16x32_bf16(a1, b1, acc[1][1], 0, 0, 0);
    cur ^= 1;
  }
  #pragma unroll
  for (int i = 0; i < 2; i++)
    #pragma unroll
    for (int j = 0; j < 2; j++)
      #pragma unroll
      for (int r = 0; r < 4; r++){
        int gm = bm + wm * 32 + i * 16 + quad * 4 + r;
        if (gm >= NF) continue;
        int gn = bn + wn * 32 + j * 16 + col;
        float v = acc[i][j][r] + bs[gn];
        v = v * 0.5f * (1.0f + erff(v * 0.70710678118654752f));
        Cb[(long)gm * FFN_ + gn] = (short)f2b(v);
      }
}

// ---- generic MFMA GEMM, double-buffered LDS (one barrier per K-step).
// MERGE=1: A[gm][k] = (sum_q Opart[q][k/32][gm][k%32]) / (sum_q Lpart[q][k/32][gm])
// ATOM=1: atomicAdd partial into Cf (bias added by z==0 block); else bf16 out + ACT.
template<int ACT, int ATOM, int MERGE>
__global__ __launch_bounds__(256) void mgemm(const short* __restrict__ A,
    const float* __restrict__ Op, const float* __restrict__ Lp,
    const short* __restrict__ W, const float* __restrict__ bs,
    float* __restrict__ Cf, short* __restrict__ Cb,
    int M, int Nn, int Kc, int Kstride){
  __shared__ __align__(16) short As[2][64][40], Ws[2][64][40];
  const int tid = threadIdx.x, lane = tid & 63, wave = tid >> 6;
  const int col = lane & 15, quad = lane >> 4;
  const int wm = wave & 1, wn = wave >> 1;
  const int bm = blockIdx.x * 64, bn = blockIdx.y * 64;
  const int koff = blockIdx.z * Kc;
  const f32x4 zero4 = {0.f, 0.f, 0.f, 0.f};
  f32x4 acc[2][2] = {{zero4, zero4}, {zero4, zero4}};
  const int row = tid >> 2, seg = tid & 3;

  auto stage = [&](int buf, int k0){
    int gm = bm + row;
    if (MERGE){
      int kg = koff + k0 + seg * 8;
      int hh = kg >> 5, d0 = kg & 31;
      short sarr[8] = {0,0,0,0,0,0,0,0};
      if (gm < M){
        float o0=0,o1=0,o2=0,o3=0,o4=0,o5=0,o6=0,o7=0, sl=0.f;
        #pragma unroll
        for (int q = 0; q < NSPLIT; q++){
          long rb = (long)(q * H_ + hh) * RPAD + gm;
          const float* op = Op + rb * HD_ + d0;
          float4 v0 = *(const float4*)op, v1 = *(const float4*)(op + 4);
          o0 += v0.x; o1 += v0.y; o2 += v0.z; o3 += v0.w;
          o4 += v1.x; o5 += v1.y; o6 += v1.z; o7 += v1.w;
          sl += Lp[rb];
        }
        float inv = 1.0f / sl;
        sarr[0]=(short)f2b(o0*inv); sarr[1]=(short)f2b(o1*inv);
        sarr[2]=(short)f2b(o2*inv); sarr[3]=(short)f2b(o3*inv);
        sarr[4]=(short)f2b(o4*inv); sarr[5]=(short)f2b(o5*inv);
        sarr[6]=(short)f2b(o6*inv); sarr[7]=(short)f2b(o7*inv);
      }
      *(bf16x8*)&As[buf][row][seg * 8] = *(bf16x8*)sarr;
    } else {
      bf16x8 av = (bf16x8)(short)0;
      if (gm < M) av = *(const bf16x8*)(A + (long)gm * Kstride + koff + k0 + seg * 8);
      *(bf16x8*)&As[buf][row][seg * 8] = av;
    }
    *(bf16x8*)&Ws[buf][row][seg * 8] =
      *(const bf16x8*)(W + (long)(bn + row) * Kstride + koff + k0 + seg * 8);
  };

  stage(0, 0);
  const int nk = Kc >> 5;
  int cur = 0;
  for (int i = 0; i < nk; i++){
    __syncthreads();
    if (i + 1 < nk) stage(cur ^ 1, (i + 1) << 5);
    bf16x8 a0 = *(const bf16x8*)&As[cur][wm * 32 + col][quad * 8];
    bf16x8 a1 = *(const bf16x8*)&As[cur][wm * 32 + 16 + col][quad * 8];
    bf16x8 b0 = *(const bf16x8*)&Ws[cur][wn * 32 + col][quad * 8];
    bf16x8 b1 = *(const bf16x8*)&Ws[cur][wn * 32 + 16 + col][quad * 8];
    acc[0][0] = __builtin_amdgcn_mfma_f32_16x16x32_bf16(a0, b0, acc[0][0], 0, 0, 0);
    acc[0][1] = __builtin_amdgcn_mfma_f32_16x16x32_bf16(a0, b1, acc[0][1], 0, 0, 0);
    acc[1][0] = __builtin_amdgcn_mfma_f32_16x16x32_bf16(a1, b0, acc[1][0], 0, 0, 0);
    acc[1][1] = __builtin_amdgcn_mfma_f32_16x16x32_bf16(a1, b1, acc[1][1], 0, 0, 0);
    cur ^= 1;
  }
  #pragma unroll
  for (int i = 0; i < 2; i++)
    #pragma unroll
    for (int j = 0; j < 2; j++)
      #pragma unroll
      for (int r = 0; r < 4; r++){
        int gm = bm + wm * 32 + i * 16 + quad * 4 + r;
        if (gm >= M) continue;
        int gn = bn + wn * 32 + j * 16 + col;
        if (ATOM){
          float v = acc[i][j][r] + (blockIdx.z == 0 ? bs[gn] : 0.f);
          atomicAdd(&Cf[(long)gm * Nn + gn], v);
        } else {
          float v = acc[i][j][r] + bs[gn];
          if (ACT == 1) v = v * 0.5f * (1.0f + erff(v * 0.70710678118654752f));
          Cb[(long)gm * Nn + gn] = (short)f2b(v);
        }
      }
}

// ---- flash attention, fixed-shift softmax in exp2 domain.
// grid (33, H, NSPLIT); block = 4 waves x 16 rows.
// Key permutation: MFMA sub-tile t4 covers key j0 + col*4 + t4, so each lane's
// 4 bias bytes per row are ONE coalesced global dword, and P is written with
// packed ds_write_b64.
// Row-sum of P comes FREE from an extra MFMA against an all-ones B fragment
// (same bf16 P values feed PV and the denominator -> exact consistency);
// K/V tiles are double-buffered so there is one barrier per tile and the
// next tile's loads overlap the current tile's softmax+PV.
// NOTE (R3 post-mortem): direct-global K/V fragments regressed 1.7x —
// per-lane fragment loads touch 16 cache lines each and quadruple VMEM
// traffic (no cross-wave sharing). LDS staging is load-SHARING; keep it.
__global__ __launch_bounds__(256) void fattn_k(const short* __restrict__ Qb,
    const short* __restrict__ Kb, const short* __restrict__ Vtg,
    const unsigned char* __restrict__ bias8, float* __restrict__ Opart,
    float* __restrict__ Lpart){
  __shared__ __align__(16) short Ks[2][64][42];  // stride 42: 2-way max on permuted reads
  __shared__ __align__(16) short Vt[2][32][72];
  __shared__ __align__(16) short Ps[4][16][72];

  const int tid = threadIdx.x, wave = tid >> 6, lane = tid & 63;
  const int col = lane & 15, quad = lane >> 4;
  const int h = blockIdx.y, qz = blockIdx.z;
  const int i0 = blockIdx.x * 64 + wave * 16;
  const int t0 = (qz == 0) ? 0 : 9 + 8 * (qz - 1);   // 0,9,17,25
  const int t1 = t0 + ((qz == 0) ? 9 : 8);           // 33 tiles total

  int qrow = min(i0 + col, NF - 1);
  bf16x8 qf = *(const bf16x8*)(Qb + (long)qrow * D_ + h * HD_ + quad * 8);

  int brow[4];
  #pragma unroll
  for (int r = 0; r < 4; r++) brow[r] = min(i0 + quad * 4 + r, NF - 1);

  f32x4 oacc0 = {0.f, 0.f, 0.f, 0.f}, oacc1 = {0.f, 0.f, 0.f, 0.f};
  f32x4 racc = {0.f, 0.f, 0.f, 0.f};
  const f32x4 zero4 = {0.f, 0.f, 0.f, 0.f};
  const bf16x8 ones8 = (bf16x8)(short)0x3F80;   // bf16 1.0 splat
  short* Pp = &Ps[wave][0][0];

  auto stageKV = [&](int buf, int t){
    int j0 = t * 64;
    { // K tile: 64 keys x 32 dims
      int key = tid >> 2, seg = tid & 3;
      int j = j0 + key;
      bf16x8 kv = (bf16x8)(short)0;
      if (j < NF) kv = *(const bf16x8*)(Kb + (long)j * D_ + h * HD_ + seg * 8);
      *(bf16x8*)&Ks[buf][key][seg * 8] = kv;
    }
    { // V tile (pre-transposed): 32 dims x 64 keys
      int d = tid >> 3, seg = tid & 7;
      *(bf16x8*)&Vt[buf][d][seg * 8] =
        *(const bf16x8*)(Vtg + (long)(h * HD_ + d) * BSTRIDE + j0 + seg * 8);
    }
  };

  stageKV(0, t0);
  int cur = 0;
  for (int t = t0; t < t1; t++){
    const int j0 = t * 64;
    // bias: one dword per row (4 fp8 bytes for t4=0..3), coalesced across col
    unsigned bw[4];
    #pragma unroll
    for (int r = 0; r < 4; r++)
      bw[r] = *(const unsigned*)(bias8 + (long)(h * NF + brow[r]) * BSTRIDE + j0 + col * 4);
    __syncthreads();
    if (t + 1 < t1) stageKV(cur ^ 1, t + 1);

    f32x4 sacc[4];
    #pragma unroll
    for (int t4 = 0; t4 < 4; t4++){
      bf16x8 kf = *(const bf16x8*)&Ks[cur][col * 4 + t4][quad * 8];
      sacc[t4] = __builtin_amdgcn_mfma_f32_16x16x32_bf16(qf, kf, zero4, 0, 0, 0);
    }

    if (j0 + 64 > NF){
      // masked tail tile (only t==32, qz==3)
      #pragma unroll
      for (int r = 0; r < 4; r++){
        unsigned w = bw[r];
        float s0 = sacc[0][r] + __builtin_amdgcn_cvt_f32_fp8((int)w, 0);
        float s1 = sacc[1][r] + __builtin_amdgcn_cvt_f32_fp8((int)w, 1);
        float s2 = sacc[2][r] + __builtin_amdgcn_cvt_f32_fp8((int)w, 2);
        float s3 = sacc[3][r] + __builtin_amdgcn_cvt_f32_fp8((int)w, 3);
        unsigned p0 = (j0 + col * 4 + 0 < NF) ? __float_as_uint(exp2f(s0)) : 0u;
        unsigned p1 = (j0 + col * 4 + 1 < NF) ? __float_as_uint(exp2f(s1)) : 0u;
        unsigned p2 = (j0 + col * 4 + 2 < NF) ? __float_as_uint(exp2f(s2)) : 0u;
        unsigned p3 = (j0 + col * 4 + 3 < NF) ? __float_as_uint(exp2f(s3)) : 0u;
        unsigned u0 = (p0 >> 16) | (p1 & 0xffff0000u);
        unsigned u1 = (p2 >> 16) | (p3 & 0xffff0000u);
        *(uint2*)&Pp[(quad * 4 + r) * 72 + col * 4] = make_uint2(u0, u1);
      }
    } else {
      #pragma unroll
      for (int r = 0; r < 4; r++){
        unsigned w = bw[r];
        float s0 = sacc[0][r] + __builtin_amdgcn_cvt_f32_fp8((int)w, 0);
        float s1 = sacc[1][r] + __builtin_amdgcn_cvt_f32_fp8((int)w, 1);
        float s2 = sacc[2][r] + __builtin_amdgcn_cvt_f32_fp8((int)w, 2);
        float s3 = sacc[3][r] + __builtin_amdgcn_cvt_f32_fp8((int)w, 3);
        unsigned p0 = __float_as_uint(exp2f(s0));
        unsigned p1 = __float_as_uint(exp2f(s1));
        unsigned p2 = __float_as_uint(exp2f(s2));
        unsigned p3 = __float_as_uint(exp2f(s3));
        unsigned u0 = (p0 >> 16) | (p1 & 0xffff0000u);
        unsigned u1 = (p2 >> 16) | (p3 & 0xffff0000u);
        *(uint2*)&Pp[(quad * 4 + r) * 72 + col * 4] = make_uint2(u0, u1);
      }
    }

    #pragma unroll
    for (int ks = 0; ks < 2; ks++){
      bf16x8 af = *(const bf16x8*)&Pp[col * 72 + ks * 32 + quad * 8];
      bf16x8 v0 = *(const bf16x8*)&Vt[cur][col][ks * 32 + quad * 8];
      bf16x8 v1 = *(const bf16x8*)&Vt[cur][16 + col][ks * 32 + quad * 8];
      oacc0 = __builtin_amdgcn_mfma_f32_16x16x32_bf16(af, v0, oacc0, 0, 0, 0);
      oacc1 = __builtin_amdgcn_mfma_f32_16x16x32_bf16(af, v1, oacc1, 0, 0, 0);
      racc  = __builtin_amdgcn_mfma_f32_16x16x32_bf16(af, ones8, racc, 0, 0, 0);
    }
    cur ^= 1;
  }

  long pi = ((long)qz * H_ + h) * RPAD + i0 + quad * 4;
  #pragma unroll
  for (int r = 0; r < 4; r++){
    Opart[(pi + r) * HD_ + col] = oacc0[r];
    Opart[(pi + r) * HD_ + 16 + col] = oacc1[r];
    if (col == 0) Lpart[pi + r] = racc[r];
  }
}

extern "C" void kernel_launch(void* const* d_in, const int* in_sizes, int n_in,
                              void* d_out, int out_size, void* d_ws, size_t ws_size,
                              hipStream_t stream){
  const float* x    = (const float*)d_in[0];
  const float* ea   = (const float*)d_in[1];
  const float* npw  = (const float*)d_in[2];
  const float* npb  = (const float*)d_in[3];
  const float* inE  = (const float*)d_in[4];
  const float* outE = (const float*)d_in[5];
  const float* db   = (const float*)d_in[6];
  const float* epw  = (const float*)d_in[7];
  const float* epb  = (const float*)d_in[8];
  const float* cls  = (const float*)d_in[9];
  const float* qw   = (const float*)d_in[10];
  const float* qb   = (const float*)d_in[11];
  const float* kw   = (const float*)d_in[12];
  const float* kb   = (const float*)d_in[13];
  const float* vw   = (const float*)d_in[14];
  const float* vb   = (const float*)d_in[15];
  const float* ow   = (const float*)d_in[16];
  const float* ob   = (const float*)d_in[17];
  const float* f1w  = (const float*)d_in[18];
  const float* f1b  = (const float*)d_in[19];
  const float* f2w  = (const float*)d_in[20];
  const float* f2bp = (const float*)d_in[21];
  const float* ln1s = (const float*)d_in[22];
  const float* ln1b = (const float*)d_in[23];
  const float* ln2s = (const float*)d_in[24];
  const float* ln2b = (const float*)d_in[25];
  const float* fns  = (const float*)d_in[26];
  const float* fnb  = (const float*)d_in[27];
  const int*   ei   = (const int*)d_in[28];
  const int*   dist = (const int*)d_in[29];

  float* ws = (float*)d_ws;
  long off = 0;
  float* h     = ws + off; off += (long)NF * D_;
  float* Opart = ws + off; off += (long)NSPLIT * H_ * RPAD * HD_;
  float* Lpart = ws + off; off += (long)NSPLIT * H_ * RPAD;
  unsigned char* bias8 = (unsigned char*)(ws + off);
  off += ((long)H_ * NF * BSTRIDE + 3) / 4;
  short* hnb   = (short*)(ws + off); off += ((long)NF * D_ + 1) / 2;  // unused (kept for layout stability)
  short* QKb   = (short*)(ws + off); off += (long)NF * D_;      // Q then K
  short* Vtg   = (short*)(ws + off); off += ((long)D_ * BSTRIDE + 1) / 2;
  short* midb  = (short*)(ws + off); off += ((long)NF * FFN_ + 1) / 2;
  short* wqkv  = (short*)(ws + off); off += ((long)3 * L_ * D_ * D_ + 1) / 2;
  short* owb   = (short*)(ws + off); off += ((long)L_ * D_ * D_ + 1) / 2;
  short* f1wb  = (short*)(ws + off); off += ((long)L_ * FFN_ * D_ + 1) / 2;
  short* f2wb  = (short*)(ws + off); off += ((long)L_ * FFN_ * D_ + 1) / 2;
  int*   ind   = (int*)(ws + off);
  int*   outd  = ind + N_;
  (void)hnb;

  zero_int<<<(2 * N_ + 255) / 256, 256, 0, stream>>>(ind, 2 * N_);
  deg_count<<<(E_ + 255) / 256, 256, 0, stream>>>(ei, ind, outd);
  embed_k<<<NF, D_, 0, stream>>>(x, npw, npb, inE, outE, ind, outd, cls, h);
  bias_fill<<<NF, 256, 0, stream>>>(dist, db, bias8);
  edge_bias<<<(E_ + 255) / 256, 256, 0, stream>>>(ea, epw, epb, ei, bias8);
  {
    long LFD = (long)L_ * FFN_ * D_;
    w2b_all<<<(int)((LFD + 255) / 256), 256, 0, stream>>>(qw, kw, vw, ow, f1w, f2w,
                                                          wqkv, owb, f1wb, f2wb);
  }

  const int gLN = (NF + 3) / 4;
  dim3 gQKV((NF + 63) / 64, D_ / 64, 3);
  dim3 gO((NF + 63) / 64, D_ / 64, 2);
  dim3 gF((NF + 63) / 64, FFN_ / 64, 1);
  dim3 gF2((NF + 63) / 64, D_ / 64, 4);
  dim3 gA((NF + 63) / 64, H_, NSPLIT);
  for (int l = 0; l < L_; l++){
    qkv_gemm<<<gQKV, 256, 0, stream>>>(h, ln1s + l * D_, ln1b + l * D_, wqkv,
                                       qb + l * D_, kb + l * D_, vb + l * D_,
                                       QKb, Vtg, l);
    fattn_k<<<gA, 256, 0, stream>>>(QKb, QKb + (long)NF * D_, Vtg, bias8, Opart, Lpart);
    mgemm<0,1,1><<<gO, 256, 0, stream>>>(nullptr, Opart, Lpart,
                                         owb + (long)l * D_ * D_, ob + l * D_,
                                         h, nullptr, NF, D_, 128, D_);
    ffn1_ln<<<gF, 256, 0, stream>>>(h, ln2s + l * D_, ln2b + l * D_,
                                    f1wb + (long)l * FFN_ * D_, f1b + l * FFN_, midb);
    mgemm<0,1,0><<<gF2, 256, 0, stream>>>(midb, nullptr, nullptr,
                                          f2wb + (long)l * FFN_ * D_, f2bp + l * D_,
                                          h, nullptr, NF, D_, 256, FFN_);
  }
  ln_k<<<gLN, 256, 0, stream>>>(h, fns, fnb, (float*)d_out, nullptr, 1, NF);
}

// Round 7
// 689.948 us; speedup vs baseline: 1.0510x; 1.0510x over previous
//
#include <hip/hip_runtime.h>
#include <math.h>

#define N_ 2048
#define NF_IN 64
#define D_ 256
#define H_ 8
#define HD_ 32
#define L_ 6
#define FFN_ 1024
#define E_ 32768
#define EF_ 16
#define NF 2049      // N+1 tokens (CLS at row 0)
#define MAXDEG_ 64
#define BSTRIDE 2112 // padded row stride: bytes for fp8 bias, shorts for Vt
#define RPAD 2176    // padded row count for attention partials (17 * 128)
#define NSPLIT 4     // key splits for flash attention
#define LOG2E 1.4426950408889634f

typedef __attribute__((ext_vector_type(8))) short bf16x8;
typedef __attribute__((ext_vector_type(4))) float f32x4;

__device__ inline unsigned short f2b(float f){
  union { float f; unsigned u; } v; v.f = f;
  unsigned r = (v.u + 0x7fffu + ((v.u >> 16) & 1u)) >> 16;
  return (unsigned short)r;
}
__device__ inline float b2f(short s){
  union { unsigned u; float f; } v; v.u = ((unsigned)(unsigned short)s) << 16;
  return v.f;
}

// manual OCP e4m3fn encode, RNE (prep-path only)
__device__ inline unsigned char f2fp8(float f){
  unsigned u = __float_as_uint(f);
  unsigned s = (u >> 24) & 0x80u;
  float a = fabsf(f);
  if (a >= 448.f) return (unsigned char)(s | 0x7Eu);
  if (a < 0.015625f){                      // denormal region (incl. 0)
    int k = (int)rintf(a * 512.f);         // step 2^-9; k=8 rolls into 2^-6
    return (unsigned char)(s | (unsigned)k);
  }
  int e; float m = frexpf(a, &e);          // a = m*2^e, m in [0.5,1)
  int E = e - 1;
  int m3 = (int)rintf(m * 16.f) - 8;       // 0..8
  if (m3 == 8){ E++; m3 = 0; }
  if (E > 8){ E = 8; m3 = 6; }
  if (E == 8 && m3 > 6) m3 = 6;
  return (unsigned char)(s | (unsigned)((E + 7) << 3) | (unsigned)m3);
}
__device__ inline float fp82f(unsigned char b){
  return __builtin_amdgcn_cvt_f32_fp8((int)b, 0);
}

__device__ inline void atomic_add_fp8(unsigned char* p, float add){
  unsigned* wp = (unsigned*)((size_t)p & ~(size_t)3);
  int sh = (int)((size_t)p & 3) * 8;
  unsigned old = *wp, assumed;
  do {
    assumed = old;
    unsigned char cur = (unsigned char)((assumed >> sh) & 0xFFu);
    float f = fp82f(cur) + add;
    unsigned nw = (assumed & ~(0xFFu << sh)) | ((unsigned)f2fp8(f) << sh);
    old = atomicCAS(wp, assumed, nw);
  } while (old != assumed);
}

__global__ void zero_int(int* p, int n){
  int i = blockIdx.x * blockDim.x + threadIdx.x;
  if (i < n) p[i] = 0;
}

__global__ void deg_count(const int* __restrict__ ei, int* __restrict__ ind,
                          int* __restrict__ outd){
  int e = blockIdx.x * blockDim.x + threadIdx.x;
  if (e >= E_) return;
  atomicAdd(&outd[ei[e]], 1);
  atomicAdd(&ind[ei[E_ + e]], 1);
}

__global__ void embed_k(const float* __restrict__ x, const float* __restrict__ W,
                        const float* __restrict__ b, const float* __restrict__ inE,
                        const float* __restrict__ outE, const int* __restrict__ ind,
                        const int* __restrict__ outd, const float* __restrict__ cls,
                        float* __restrict__ h){
  int i = blockIdx.x, d = threadIdx.x;
  if (i == 0){ h[d] = cls[d]; return; }
  int n = i - 1;
  const float4* xr = (const float4*)(x + (long)n * NF_IN);
  const float4* wr = (const float4*)(W + (long)d * NF_IN);
  float acc = b[d];
  #pragma unroll
  for (int k = 0; k < NF_IN / 4; k++){
    float4 a = xr[k], w = wr[k];
    acc += a.x * w.x + a.y * w.y + a.z * w.z + a.w * w.w;
  }
  int id = min(ind[n], MAXDEG_), od = min(outd[n], MAXDEG_);
  acc += inE[(long)id * D_ + d] + outE[(long)od * D_ + d];
  h[(long)i * D_ + d] = acc;
}

// bias stored as fp8 of (bias * log2e) — exp2-domain; grid NF
__global__ void bias_fill(const int* __restrict__ dist, const float* __restrict__ db,
                          unsigned char* __restrict__ bb){
  __shared__ unsigned char lut8[10][H_];
  int i = blockIdx.x;
  if (threadIdx.x < 80)
    ((unsigned char*)lut8)[threadIdx.x] = f2fp8(db[threadIdx.x] * LOG2E);
  __syncthreads();
  for (int u = threadIdx.x; u < BSTRIDE / 8; u += 256){
    int dp[8];
    #pragma unroll
    for (int k = 0; k < 8; k++){
      int j = u * 8 + k;
      int d = 0;
      if (i > 0 && j > 0 && j < NF){
        int dv = dist[(long)(i - 1) * N_ + (j - 1)];
        d = max(0, min(dv, 9));
      }
      dp[k] = (j < NF) ? d : -1;
    }
    #pragma unroll
    for (int h = 0; h < H_; h++){
      unsigned lo = 0, hi = 0;
      #pragma unroll
      for (int k = 0; k < 4; k++){
        unsigned b0 = (dp[k] >= 0) ? lut8[dp[k]][h] : 0u;
        unsigned b1 = (dp[4 + k] >= 0) ? lut8[dp[4 + k]][h] : 0u;
        lo |= b0 << (8 * k);
        hi |= b1 << (8 * k);
      }
      *(uint2*)(bb + ((long)h * NF + i) * BSTRIDE + u * 8) = make_uint2(lo, hi);
    }
  }
}

// sparse edge-feature bias: byte-CAS fp8 add (also log2e-scaled)
__global__ void edge_bias(const float* __restrict__ ea, const float* __restrict__ W,
                          const float* __restrict__ b, const int* __restrict__ ei,
                          unsigned char* __restrict__ bb){
  int e = blockIdx.x * blockDim.x + threadIdx.x;
  if (e >= E_) return;
  float a[EF_];
  #pragma unroll
  for (int k = 0; k < EF_; k++) a[k] = ea[(long)e * EF_ + k];
  int src = ei[e], dst = ei[E_ + e];
  #pragma unroll
  for (int h = 0; h < H_; h++){
    float p = b[h];
    #pragma unroll
    for (int k = 0; k < EF_; k++) p += a[k] * W[h * EF_ + k];
    atomic_add_fp8(bb + ((long)h * NF + src + 1) * BSTRIDE + (dst + 1), p * LOG2E);
  }
}

// all weight conversions in one dispatch
__global__ void w2b_all(const float* __restrict__ qw, const float* __restrict__ kw,
                        const float* __restrict__ vw, const float* __restrict__ ow,
                        const float* __restrict__ f1w, const float* __restrict__ f2w,
                        short* __restrict__ wqkv, short* __restrict__ owb,
                        short* __restrict__ f1wb, short* __restrict__ f2wb){
  long i = (long)blockIdx.x * 256 + threadIdx.x;
  const long DD = (long)D_ * D_, LDD = (long)L_ * DD, LFD = (long)L_ * FFN_ * D_;
  if (i < LDD){
    long l = i / DD, r = i - l * DD;
    wqkv[l * 3 * DD + r]          = (short)f2b(qw[i]);
    wqkv[l * 3 * DD + DD + r]     = (short)f2b(kw[i]);
    wqkv[l * 3 * DD + 2 * DD + r] = (short)f2b(vw[i]);
    owb[i] = (short)f2b(ow[i]);
  }
  if (i < LFD){
    f1wb[i] = (short)f2b(f1w[i]);
    f2wb[i] = (short)f2b(f2w[i]);
  }
}

// wave-per-row layernorm: 4 rows/block, no LDS, no barriers.
// (R6 post-mortem: fusing LN into GEMM prologues recomputes it 12-16x per
// row tile and re-reads h as many times — regressed 59us. Graph-captured
// dispatches are cheap; keep LN as its own kernel.)
__global__ __launch_bounds__(256) void ln_k(const float* __restrict__ in,
                     const float* __restrict__ s, const float* __restrict__ b,
                     float* __restrict__ outf, short* __restrict__ outb,
                     int dup0, int M){
  int row = blockIdx.x * 4 + (threadIdx.x >> 6);
  int lane = threadIdx.x & 63;
  if (row >= M) return;
  float4 v = *(const float4*)(in + (long)row * D_ + lane * 4);
  float s1 = v.x + v.y + v.z + v.w;
  float s2 = v.x * v.x + v.y * v.y + v.z * v.z + v.w * v.w;
  #pragma unroll
  for (int o = 1; o < 64; o <<= 1){
    s1 += __shfl_xor(s1, o, 64);
    s2 += __shfl_xor(s2, o, 64);
  }
  float m = s1 * (1.0f / D_);
  float var = s2 * (1.0f / D_) - m * m;
  float rstd = rsqrtf(var + 1e-5f);
  float4 sc = *(const float4*)(s + lane * 4);
  float4 bb = *(const float4*)(b + lane * 4);
  float y0 = (v.x - m) * rstd * sc.x + bb.x;
  float y1 = (v.y - m) * rstd * sc.y + bb.y;
  float y2 = (v.z - m) * rstd * sc.z + bb.z;
  float y3 = (v.w - m) * rstd * sc.w + bb.w;
  if (outf){
    float4 o4 = make_float4(y0, y1, y2, y3);
    *(float4*)(outf + (long)row * D_ + lane * 4) = o4;
    if (dup0 && row == 0) *(float4*)(outf + (long)NF * D_ + lane * 4) = o4;
  }
  if (outb){
    short4 pk;
    pk.x = (short)f2b(y0); pk.y = (short)f2b(y1);
    pk.z = (short)f2b(y2); pk.w = (short)f2b(y3);
    *(short4*)(outb + (long)row * D_ + lane * 4) = pk;
  }
}

// ---- fused QKV MFMA GEMM: grid (33, 4, 3). z==0 (Q) is pre-scaled by
// (1/sqrt(HD))*log2e so fattn's softmax works in the exp2 domain.
// z==2 (V): epilogue transposes the 64x64 tile through LDS so Vtg rows are
// written with coalesced 128B segments.
// Double-buffered LDS: one barrier per K-step, next tile staged before compute.
__global__ __launch_bounds__(256) void qkv_gemm(const short* __restrict__ A,
    const short* __restrict__ Wall, const float* __restrict__ qb,
    const float* __restrict__ kb, const float* __restrict__ vb,
    short* __restrict__ QKb, short* __restrict__ Vtg, int l){
  const int z = blockIdx.z;
  const short* W = Wall + ((long)(l * 3 + z)) * D_ * D_;
  const float* bsp = (z == 0) ? qb : (z == 1) ? kb : vb;
  __shared__ __align__(16) short As[2][64][40], Ws[2][64][40];
  __shared__ __align__(16) short Tt[64][72];   // V transpose buffer [dim][key]
  const int tid = threadIdx.x, lane = tid & 63, wave = tid >> 6;
  const int col = lane & 15, quad = lane >> 4;
  const int wm = wave & 1, wn = wave >> 1;
  const int bm = blockIdx.x * 64, bn = blockIdx.y * 64;
  const f32x4 zero4 = {0.f, 0.f, 0.f, 0.f};
  f32x4 acc[2][2] = {{zero4, zero4}, {zero4, zero4}};
  const int row = tid >> 2, seg = tid & 3;

  auto stage = [&](int buf, int k0){
    bf16x8 av = (bf16x8)(short)0;
    int gm = bm + row;
    if (gm < NF) av = *(const bf16x8*)(A + (long)gm * D_ + k0 + seg * 8);
    *(bf16x8*)&As[buf][row][seg * 8] = av;
    *(bf16x8*)&Ws[buf][row][seg * 8] =
      *(const bf16x8*)(W + (long)(bn + row) * D_ + k0 + seg * 8);
  };

  stage(0, 0);
  int cur = 0;
  for (int k0 = 0; k0 < D_; k0 += 32){
    __syncthreads();
    if (k0 + 32 < D_) stage(cur ^ 1, k0 + 32);
    bf16x8 a0 = *(const bf16x8*)&As[cur][wm * 32 + col][quad * 8];
    bf16x8 a1 = *(const bf16x8*)&As[cur][wm * 32 + 16 + col][quad * 8];
    bf16x8 b0 = *(const bf16x8*)&Ws[cur][wn * 32 + col][quad * 8];
    bf16x8 b1 = *(const bf16x8*)&Ws[cur][wn * 32 + 16 + col][quad * 8];
    acc[0][0] = __builtin_amdgcn_mfma_f32_16x16x32_bf16(a0, b0, acc[0][0], 0, 0, 0);
    acc[0][1] = __builtin_amdgcn_mfma_f32_16x16x32_bf16(a0, b1, acc[0][1], 0, 0, 0);
    acc[1][0] = __builtin_amdgcn_mfma_f32_16x16x32_bf16(a1, b0, acc[1][0], 0, 0, 0);
    acc[1][1] = __builtin_amdgcn_mfma_f32_16x16x32_bf16(a1, b1, acc[1][1], 0, 0, 0);
    cur ^= 1;
  }
  if (z < 2){
    const float qscale = 0.25501133194822025f;  // (1/sqrt(32)) * log2e
    #pragma unroll
    for (int i = 0; i < 2; i++)
      #pragma unroll
      for (int j = 0; j < 2; j++)
        #pragma unroll
        for (int r = 0; r < 4; r++){
          int gm = bm + wm * 32 + i * 16 + quad * 4 + r;
          if (gm >= NF) continue;
          int gn = bn + wn * 32 + j * 16 + col;
          float v = acc[i][j][r] + bsp[gn];
          if (z == 0) v *= qscale;
          QKb[(long)z * NF * D_ + (long)gm * D_ + gn] = (short)f2b(v);
        }
  } else {
    // transpose tile into LDS: Tt[dim][key]; rows gm>=NF hold finite values
    #pragma unroll
    for (int i = 0; i < 2; i++)
      #pragma unroll
      for (int j = 0; j < 2; j++){
        int ln_ = wn * 32 + j * 16 + col;     // local dim
        int lc = wm * 32 + i * 16 + quad * 4; // local key base (4 consecutive)
        float bsv = bsp[bn + ln_];
        short pk[4];
        #pragma unroll
        for (int r = 0; r < 4; r++) pk[r] = (short)f2b(acc[i][j][r] + bsv);
        *(short4*)&Tt[ln_][lc] = *(short4*)pk;
      }
    __syncthreads();
    int lr = tid >> 2, sg = tid & 3;
    bf16x8 v0 = *(const bf16x8*)&Tt[lr][sg * 16];
    bf16x8 v1 = *(const bf16x8*)&Tt[lr][sg * 16 + 8];
    short* dstp = Vtg + (long)(bn + lr) * BSTRIDE + bm + sg * 16;
    *(bf16x8*)dstp = v0;
    *(bf16x8*)(dstp + 8) = v1;
  }
}

// ---- generic MFMA GEMM, double-buffered LDS (one barrier per K-step).
// MERGE=1: A[gm][k] = (sum_q Opart[q][k/32][gm][k%32]) / (sum_q Lpart[q][k/32][gm])
// ATOM=1: atomicAdd partial into Cf (bias added by z==0 block); else bf16 out + ACT.
template<int ACT, int ATOM, int MERGE>
__global__ __launch_bounds__(256) void mgemm(const short* __restrict__ A,
    const float* __restrict__ Op, const float* __restrict__ Lp,
    const short* __restrict__ W, const float* __restrict__ bs,
    float* __restrict__ Cf, short* __restrict__ Cb,
    int M, int Nn, int Kc, int Kstride){
  __shared__ __align__(16) short As[2][64][40], Ws[2][64][40];
  const int tid = threadIdx.x, lane = tid & 63, wave = tid >> 6;
  const int col = lane & 15, quad = lane >> 4;
  const int wm = wave & 1, wn = wave >> 1;
  const int bm = blockIdx.x * 64, bn = blockIdx.y * 64;
  const int koff = blockIdx.z * Kc;
  const f32x4 zero4 = {0.f, 0.f, 0.f, 0.f};
  f32x4 acc[2][2] = {{zero4, zero4}, {zero4, zero4}};
  const int row = tid >> 2, seg = tid & 3;

  auto stage = [&](int buf, int k0){
    int gm = bm + row;
    if (MERGE){
      int kg = koff + k0 + seg * 8;
      int hh = kg >> 5, d0 = kg & 31;
      short sarr[8] = {0,0,0,0,0,0,0,0};
      if (gm < M){
        float o0=0,o1=0,o2=0,o3=0,o4=0,o5=0,o6=0,o7=0, sl=0.f;
        #pragma unroll
        for (int q = 0; q < NSPLIT; q++){
          long rb = (long)(q * H_ + hh) * RPAD + gm;
          const float* op = Op + rb * HD_ + d0;
          float4 v0 = *(const float4*)op, v1 = *(const float4*)(op + 4);
          o0 += v0.x; o1 += v0.y; o2 += v0.z; o3 += v0.w;
          o4 += v1.x; o5 += v1.y; o6 += v1.z; o7 += v1.w;
          sl += Lp[rb];
        }
        float inv = 1.0f / sl;
        sarr[0]=(short)f2b(o0*inv); sarr[1]=(short)f2b(o1*inv);
        sarr[2]=(short)f2b(o2*inv); sarr[3]=(short)f2b(o3*inv);
        sarr[4]=(short)f2b(o4*inv); sarr[5]=(short)f2b(o5*inv);
        sarr[6]=(short)f2b(o6*inv); sarr[7]=(short)f2b(o7*inv);
      }
      *(bf16x8*)&As[buf][row][seg * 8] = *(bf16x8*)sarr;
    } else {
      bf16x8 av = (bf16x8)(short)0;
      if (gm < M) av = *(const bf16x8*)(A + (long)gm * Kstride + koff + k0 + seg * 8);
      *(bf16x8*)&As[buf][row][seg * 8] = av;
    }
    *(bf16x8*)&Ws[buf][row][seg * 8] =
      *(const bf16x8*)(W + (long)(bn + row) * Kstride + koff + k0 + seg * 8);
  };

  stage(0, 0);
  const int nk = Kc >> 5;
  int cur = 0;
  for (int i = 0; i < nk; i++){
    __syncthreads();
    if (i + 1 < nk) stage(cur ^ 1, (i + 1) << 5);
    bf16x8 a0 = *(const bf16x8*)&As[cur][wm * 32 + col][quad * 8];
    bf16x8 a1 = *(const bf16x8*)&As[cur][wm * 32 + 16 + col][quad * 8];
    bf16x8 b0 = *(const bf16x8*)&Ws[cur][wn * 32 + col][quad * 8];
    bf16x8 b1 = *(const bf16x8*)&Ws[cur][wn * 32 + 16 + col][quad * 8];
    acc[0][0] = __builtin_amdgcn_mfma_f32_16x16x32_bf16(a0, b0, acc[0][0], 0, 0, 0);
    acc[0][1] = __builtin_amdgcn_mfma_f32_16x16x32_bf16(a0, b1, acc[0][1], 0, 0, 0);
    acc[1][0] = __builtin_amdgcn_mfma_f32_16x16x32_bf16(a1, b0, acc[1][0], 0, 0, 0);
    acc[1][1] = __builtin_amdgcn_mfma_f32_16x16x32_bf16(a1, b1, acc[1][1], 0, 0, 0);
    cur ^= 1;
  }
  #pragma unroll
  for (int i = 0; i < 2; i++)
    #pragma unroll
    for (int j = 0; j < 2; j++)
      #pragma unroll
      for (int r = 0; r < 4; r++){
        int gm = bm + wm * 32 + i * 16 + quad * 4 + r;
        if (gm >= M) continue;
        int gn = bn + wn * 32 + j * 16 + col;
        if (ATOM){
          float v = acc[i][j][r] + (blockIdx.z == 0 ? bs[gn] : 0.f);
          atomicAdd(&Cf[(long)gm * Nn + gn], v);
        } else {
          float v = acc[i][j][r] + bs[gn];
          if (ACT == 1) v = v * 0.5f * (1.0f + erff(v * 0.70710678118654752f));
          Cb[(long)gm * Nn + gn] = (short)f2b(v);
        }
      }
}

// ---- flash attention, fixed-shift softmax in exp2 domain.
// grid (17, H, NSPLIT); block = 4 waves x 32 Q-rows = 128 rows/block.
// Each staged K/V tile + barrier now feeds 2x the Q-rows of the old 64-row
// block: kf/v fragments are read from LDS once and used by both row-halves,
// and block count halves -> K/V global fetch + LDS writes + barriers per
// Q-row all halve. Row math is identical to the 64-row version.
// Row-sum of P via MFMA vs all-ones B (bit-exact with PV).
// NOTE (R3 post-mortem): direct-global K/V fragments regressed 1.7x; LDS
// staging is load-SHARING across waves; keep it.
__global__ __launch_bounds__(256) void fattn_k(const short* __restrict__ Qb,
    const short* __restrict__ Kb, const short* __restrict__ Vtg,
    const unsigned char* __restrict__ bias8, float* __restrict__ Opart,
    float* __restrict__ Lpart){
  __shared__ __align__(16) short Ks[2][64][42];  // stride 42: 2-way max on permuted reads
  __shared__ __align__(16) short Vt[2][32][72];
  __shared__ __align__(16) short Ps[4][32][72];

  const int tid = threadIdx.x, wave = tid >> 6, lane = tid & 63;
  const int col = lane & 15, quad = lane >> 4;
  const int h = blockIdx.y, qz = blockIdx.z;
  const int i0 = blockIdx.x * 128 + wave * 32;
  const int t0 = (qz == 0) ? 0 : 9 + 8 * (qz - 1);   // 0,9,17,25
  const int t1 = t0 + ((qz == 0) ? 9 : 8);           // 33 tiles total

  int qrow0 = min(i0 + col, NF - 1);
  int qrow1 = min(i0 + 16 + col, NF - 1);
  bf16x8 qf0 = *(const bf16x8*)(Qb + (long)qrow0 * D_ + h * HD_ + quad * 8);
  bf16x8 qf1 = *(const bf16x8*)(Qb + (long)qrow1 * D_ + h * HD_ + quad * 8);

  int brow0[4], brow1[4];
  #pragma unroll
  for (int r = 0; r < 4; r++){
    brow0[r] = min(i0 + quad * 4 + r, NF - 1);
    brow1[r] = min(i0 + 16 + quad * 4 + r, NF - 1);
  }

  f32x4 oacc00 = {0.f,0.f,0.f,0.f}, oacc01 = {0.f,0.f,0.f,0.f};
  f32x4 oacc10 = {0.f,0.f,0.f,0.f}, oacc11 = {0.f,0.f,0.f,0.f};
  f32x4 racc0 = {0.f,0.f,0.f,0.f}, racc1 = {0.f,0.f,0.f,0.f};
  const f32x4 zero4 = {0.f, 0.f, 0.f, 0.f};
  const bf16x8 ones8 = (bf16x8)(short)0x3F80;   // bf16 1.0 splat
  short* Pp = &Ps[wave][0][0];

  auto stageKV = [&](int buf, int t){
    int j0 = t * 64;
    { // K tile: 64 keys x 32 dims
      int key = tid >> 2, seg = tid & 3;
      int j = j0 + key;
      bf16x8 kv = (bf16x8)(short)0;
      if (j < NF) kv = *(const bf16x8*)(Kb + (long)j * D_ + h * HD_ + seg * 8);
      *(bf16x8*)&Ks[buf][key][seg * 8] = kv;
    }
    { // V tile (pre-transposed): 32 dims x 64 keys
      int d = tid >> 3, seg = tid & 7;
      *(bf16x8*)&Vt[buf][d][seg * 8] =
        *(const bf16x8*)(Vtg + (long)(h * HD_ + d) * BSTRIDE + j0 + seg * 8);
    }
  };

  stageKV(0, t0);
  int cur = 0;
  for (int t = t0; t < t1; t++){
    const int j0 = t * 64;
    // bias: one dword per row (4 fp8 bytes for t4=0..3), coalesced across col
    unsigned bw0[4], bw1[4];
    #pragma unroll
    for (int r = 0; r < 4; r++){
      bw0[r] = *(const unsigned*)(bias8 + (long)(h * NF + brow0[r]) * BSTRIDE + j0 + col * 4);
      bw1[r] = *(const unsigned*)(bias8 + (long)(h * NF + brow1[r]) * BSTRIDE + j0 + col * 4);
    }
    __syncthreads();
    if (t + 1 < t1) stageKV(cur ^ 1, t + 1);

    f32x4 sacc0[4], sacc1[4];
    #pragma unroll
    for (int t4 = 0; t4 < 4; t4++){
      bf16x8 kf = *(const bf16x8*)&Ks[cur][col * 4 + t4][quad * 8];
      sacc0[t4] = __builtin_amdgcn_mfma_f32_16x16x32_bf16(qf0, kf, zero4, 0, 0, 0);
      sacc1[t4] = __builtin_amdgcn_mfma_f32_16x16x32_bf16(qf1, kf, zero4, 0, 0, 0);
    }

    const bool tail = (j0 + 64 > NF);   // only t==32 (qz==3)
    #pragma unroll
    for (int half = 0; half < 2; half++){
      f32x4* sp = half ? sacc1 : sacc0;
      unsigned* bp = half ? bw1 : bw0;
      int rbase = half * 16;
      if (tail){
        #pragma unroll
        for (int r = 0; r < 4; r++){
          unsigned w = bp[r];
          float s0 = sp[0][r] + __builtin_amdgcn_cvt_f32_fp8((int)w, 0);
          float s1 = sp[1][r] + __builtin_amdgcn_cvt_f32_fp8((int)w, 1);
          float s2 = sp[2][r] + __builtin_amdgcn_cvt_f32_fp8((int)w, 2);
          float s3 = sp[3][r] + __builtin_amdgcn_cvt_f32_fp8((int)w, 3);
          unsigned p0 = (j0 + col * 4 + 0 < NF) ? __float_as_uint(exp2f(s0)) : 0u;
          unsigned p1 = (j0 + col * 4 + 1 < NF) ? __float_as_uint(exp2f(s1)) : 0u;
          unsigned p2 = (j0 + col * 4 + 2 < NF) ? __float_as_uint(exp2f(s2)) : 0u;
          unsigned p3 = (j0 + col * 4 + 3 < NF) ? __float_as_uint(exp2f(s3)) : 0u;
          unsigned u0 = (p0 >> 16) | (p1 & 0xffff0000u);
          unsigned u1 = (p2 >> 16) | (p3 & 0xffff0000u);
          *(uint2*)&Pp[(rbase + quad * 4 + r) * 72 + col * 4] = make_uint2(u0, u1);
        }
      } else {
        #pragma unroll
        for (int r = 0; r < 4; r++){
          unsigned w = bp[r];
          float s0 = sp[0][r] + __builtin_amdgcn_cvt_f32_fp8((int)w, 0);
          float s1 = sp[1][r] + __builtin_amdgcn_cvt_f32_fp8((int)w, 1);
          float s2 = sp[2][r] + __builtin_amdgcn_cvt_f32_fp8((int)w, 2);
          float s3 = sp[3][r] + __builtin_amdgcn_cvt_f32_fp8((int)w, 3);
          unsigned p0 = __float_as_uint(exp2f(s0));
          unsigned p1 = __float_as_uint(exp2f(s1));
          unsigned p2 = __float_as_uint(exp2f(s2));
          unsigned p3 = __float_as_uint(exp2f(s3));
          unsigned u0 = (p0 >> 16) | (p1 & 0xffff0000u);
          unsigned u1 = (p2 >> 16) | (p3 & 0xffff0000u);
          *(uint2*)&Pp[(rbase + quad * 4 + r) * 72 + col * 4] = make_uint2(u0, u1);
        }
      }
    }

    #pragma unroll
    for (int ks = 0; ks < 2; ks++){
      bf16x8 af0 = *(const bf16x8*)&Pp[col * 72 + ks * 32 + quad * 8];
      bf16x8 af1 = *(const bf16x8*)&Pp[(16 + col) * 72 + ks * 32 + quad * 8];
      bf16x8 v0 = *(const bf16x8*)&Vt[cur][col][ks * 32 + quad * 8];
      bf16x8 v1 = *(const bf16x8*)&Vt[cur][16 + col][ks * 32 + quad * 8];
      oacc00 = __builtin_amdgcn_mfma_f32_16x16x32_bf16(af0, v0, oacc00, 0, 0, 0);
      oacc01 = __builtin_amdgcn_mfma_f32_16x16x32_bf16(af0, v1, oacc01, 0, 0, 0);
      oacc10 = __builtin_amdgcn_mfma_f32_16x16x32_bf16(af1, v0, oacc10, 0, 0, 0);
      oacc11 = __builtin_amdgcn_mfma_f32_16x16x32_bf16(af1, v1, oacc11, 0, 0, 0);
      racc0  = __builtin_amdgcn_mfma_f32_16x16x32_bf16(af0, ones8, racc0, 0, 0, 0);
      racc1  = __builtin_amdgcn_mfma_f32_16x16x32_bf16(af1, ones8, racc1, 0, 0, 0);
    }
    cur ^= 1;
  }

  long pi = ((long)qz * H_ + h) * RPAD + i0 + quad * 4;
  #pragma unroll
  for (int r = 0; r < 4; r++){
    Opart[(pi + r) * HD_ + col] = oacc00[r];
    Opart[(pi + r) * HD_ + 16 + col] = oacc01[r];
    Opart[(pi + 16 + r) * HD_ + col] = oacc10[r];
    Opart[(pi + 16 + r) * HD_ + 16 + col] = oacc11[r];
    if (col == 0){
      Lpart[pi + r] = racc0[r];
      Lpart[pi + 16 + r] = racc1[r];
    }
  }
}

extern "C" void kernel_launch(void* const* d_in, const int* in_sizes, int n_in,
                              void* d_out, int out_size, void* d_ws, size_t ws_size,
                              hipStream_t stream){
  const float* x    = (const float*)d_in[0];
  const float* ea   = (const float*)d_in[1];
  const float* npw  = (const float*)d_in[2];
  const float* npb  = (const float*)d_in[3];
  const float* inE  = (const float*)d_in[4];
  const float* outE = (const float*)d_in[5];
  const float* db   = (const float*)d_in[6];
  const float* epw  = (const float*)d_in[7];
  const float* epb  = (const float*)d_in[8];
  const float* cls  = (const float*)d_in[9];
  const float* qw   = (const float*)d_in[10];
  const float* qb   = (const float*)d_in[11];
  const float* kw   = (const float*)d_in[12];
  const float* kb   = (const float*)d_in[13];
  const float* vw   = (const float*)d_in[14];
  const float* vb   = (const float*)d_in[15];
  const float* ow   = (const float*)d_in[16];
  const float* ob   = (const float*)d_in[17];
  const float* f1w  = (const float*)d_in[18];
  const float* f1b  = (const float*)d_in[19];
  const float* f2w  = (const float*)d_in[20];
  const float* f2bp = (const float*)d_in[21];
  const float* ln1s = (const float*)d_in[22];
  const float* ln1b = (const float*)d_in[23];
  const float* ln2s = (const float*)d_in[24];
  const float* ln2b = (const float*)d_in[25];
  const float* fns  = (const float*)d_in[26];
  const float* fnb  = (const float*)d_in[27];
  const int*   ei   = (const int*)d_in[28];
  const int*   dist = (const int*)d_in[29];

  float* ws = (float*)d_ws;
  long off = 0;
  float* h     = ws + off; off += (long)NF * D_;
  float* Opart = ws + off; off += (long)NSPLIT * H_ * RPAD * HD_;
  float* Lpart = ws + off; off += (long)NSPLIT * H_ * RPAD;
  unsigned char* bias8 = (unsigned char*)(ws + off);
  off += ((long)H_ * NF * BSTRIDE + 3) / 4;
  short* hnb   = (short*)(ws + off); off += ((long)NF * D_ + 1) / 2;
  short* QKb   = (short*)(ws + off); off += (long)NF * D_;      // Q then K
  short* Vtg   = (short*)(ws + off); off += ((long)D_ * BSTRIDE + 1) / 2;
  short* midb  = (short*)(ws + off); off += ((long)NF * FFN_ + 1) / 2;
  short* wqkv  = (short*)(ws + off); off += ((long)3 * L_ * D_ * D_ + 1) / 2;
  short* owb   = (short*)(ws + off); off += ((long)L_ * D_ * D_ + 1) / 2;
  short* f1wb  = (short*)(ws + off); off += ((long)L_ * FFN_ * D_ + 1) / 2;
  short* f2wb  = (short*)(ws + off); off += ((long)L_ * FFN_ * D_ + 1) / 2;
  int*   ind   = (int*)(ws + off);
  int*   outd  = ind + N_;

  zero_int<<<(2 * N_ + 255) / 256, 256, 0, stream>>>(ind, 2 * N_);
  deg_count<<<(E_ + 255) / 256, 256, 0, stream>>>(ei, ind, outd);
  embed_k<<<NF, D_, 0, stream>>>(x, npw, npb, inE, outE, ind, outd, cls, h);
  bias_fill<<<NF, 256, 0, stream>>>(dist, db, bias8);
  edge_bias<<<(E_ + 255) / 256, 256, 0, stream>>>(ea, epw, epb, ei, bias8);
  {
    long LFD = (long)L_ * FFN_ * D_;
    w2b_all<<<(int)((LFD + 255) / 256), 256, 0, stream>>>(qw, kw, vw, ow, f1w, f2w,
                                                          wqkv, owb, f1wb, f2wb);
  }

  const int gLN = (NF + 3) / 4;
  dim3 gQKV((NF + 63) / 64, D_ / 64, 3);
  dim3 gO((NF + 63) / 64, D_ / 64, 2);
  dim3 gF((NF + 63) / 64, FFN_ / 64, 1);
  dim3 gF2((NF + 63) / 64, D_ / 64, 4);
  dim3 gA((NF + 127) / 128, H_, NSPLIT);
  for (int l = 0; l < L_; l++){
    ln_k<<<gLN, 256, 0, stream>>>(h, ln1s + l * D_, ln1b + l * D_, nullptr, hnb, 0, NF);
    qkv_gemm<<<gQKV, 256, 0, stream>>>(hnb, wqkv, qb + l * D_, kb + l * D_, vb + l * D_,
                                       QKb, Vtg, l);
    fattn_k<<<gA, 256, 0, stream>>>(QKb, QKb + (long)NF * D_, Vtg, bias8, Opart, Lpart);
    mgemm<0,1,1><<<gO, 256, 0, stream>>>(nullptr, Opart, Lpart,
                                         owb + (long)l * D_ * D_, ob + l * D_,
                                         h, nullptr, NF, D_, 128, D_);
    ln_k<<<gLN, 256, 0, stream>>>(h, ln2s + l * D_, ln2b + l * D_, nullptr, hnb, 0, NF);
    mgemm<1,0,0><<<gF, 256, 0, stream>>>(hnb, nullptr, nullptr,
                                         f1wb + (long)l * FFN_ * D_, f1b + l * FFN_,
                                         nullptr, midb, NF, FFN_, D_, D_);
    mgemm<0,1,0><<<gF2, 256, 0, stream>>>(midb, nullptr, nullptr,
                                          f2wb + (long)l * FFN_ * D_, f2bp + l * D_,
                                          h, nullptr, NF, D_, 256, FFN_);
  }
  ln_k<<<gLN, 256, 0, stream>>>(h, fns, fnb, (float*)d_out, nullptr, 1, NF);
}

// Round 8
// 623.376 us; speedup vs baseline: 1.1632x; 1.1068x over previous
//
#include <hip/hip_runtime.h>
#include <math.h>

#define N_ 2048
#define NF_IN 64
#define D_ 256
#define H_ 8
#define HD_ 32
#define L_ 6
#define FFN_ 1024
#define E_ 32768
#define EF_ 16
#define NF 2049      // N+1 tokens (CLS at row 0)
#define MAXDEG_ 64
#define BSTRIDE 2112 // padded row stride: bytes for fp8 bias, shorts for Vt
#define RPAD 2112    // padded row count for attention partials
#define NSPLIT 4     // key splits for flash attention
#define LOG2E 1.4426950408889634f

typedef __attribute__((ext_vector_type(8))) short bf16x8;
typedef __attribute__((ext_vector_type(4))) float f32x4;

__device__ inline unsigned short f2b(float f){
  union { float f; unsigned u; } v; v.f = f;
  unsigned r = (v.u + 0x7fffu + ((v.u >> 16) & 1u)) >> 16;
  return (unsigned short)r;
}
__device__ inline float b2f(short s){
  union { unsigned u; float f; } v; v.u = ((unsigned)(unsigned short)s) << 16;
  return v.f;
}

// manual OCP e4m3fn encode, RNE (prep-path only)
__device__ inline unsigned char f2fp8(float f){
  unsigned u = __float_as_uint(f);
  unsigned s = (u >> 24) & 0x80u;
  float a = fabsf(f);
  if (a >= 448.f) return (unsigned char)(s | 0x7Eu);
  if (a < 0.015625f){                      // denormal region (incl. 0)
    int k = (int)rintf(a * 512.f);         // step 2^-9; k=8 rolls into 2^-6
    return (unsigned char)(s | (unsigned)k);
  }
  int e; float m = frexpf(a, &e);          // a = m*2^e, m in [0.5,1)
  int E = e - 1;
  int m3 = (int)rintf(m * 16.f) - 8;       // 0..8
  if (m3 == 8){ E++; m3 = 0; }
  if (E > 8){ E = 8; m3 = 6; }
  if (E == 8 && m3 > 6) m3 = 6;
  return (unsigned char)(s | (unsigned)((E + 7) << 3) | (unsigned)m3);
}
__device__ inline float fp82f(unsigned char b){
  return __builtin_amdgcn_cvt_f32_fp8((int)b, 0);
}

__device__ inline void atomic_add_fp8(unsigned char* p, float add){
  unsigned* wp = (unsigned*)((size_t)p & ~(size_t)3);
  int sh = (int)((size_t)p & 3) * 8;
  unsigned old = *wp, assumed;
  do {
    assumed = old;
    unsigned char cur = (unsigned char)((assumed >> sh) & 0xFFu);
    float f = fp82f(cur) + add;
    unsigned nw = (assumed & ~(0xFFu << sh)) | ((unsigned)f2fp8(f) << sh);
    old = atomicCAS(wp, assumed, nw);
  } while (old != assumed);
}

__global__ void zero_int(int* p, int n){
  int i = blockIdx.x * blockDim.x + threadIdx.x;
  if (i < n) p[i] = 0;
}

__global__ void deg_count(const int* __restrict__ ei, int* __restrict__ ind,
                          int* __restrict__ outd){
  int e = blockIdx.x * blockDim.x + threadIdx.x;
  if (e >= E_) return;
  atomicAdd(&outd[ei[e]], 1);
  atomicAdd(&ind[ei[E_ + e]], 1);
}

__global__ void embed_k(const float* __restrict__ x, const float* __restrict__ W,
                        const float* __restrict__ b, const float* __restrict__ inE,
                        const float* __restrict__ outE, const int* __restrict__ ind,
                        const int* __restrict__ outd, const float* __restrict__ cls,
                        float* __restrict__ h){
  int i = blockIdx.x, d = threadIdx.x;
  if (i == 0){ h[d] = cls[d]; return; }
  int n = i - 1;
  const float4* xr = (const float4*)(x + (long)n * NF_IN);
  const float4* wr = (const float4*)(W + (long)d * NF_IN);
  float acc = b[d];
  #pragma unroll
  for (int k = 0; k < NF_IN / 4; k++){
    float4 a = xr[k], w = wr[k];
    acc += a.x * w.x + a.y * w.y + a.z * w.z + a.w * w.w;
  }
  int id = min(ind[n], MAXDEG_), od = min(outd[n], MAXDEG_);
  acc += inE[(long)id * D_ + d] + outE[(long)od * D_ + d];
  h[(long)i * D_ + d] = acc;
}

// bias stored as fp8 of (bias * log2e) — exp2-domain; grid NF
__global__ void bias_fill(const int* __restrict__ dist, const float* __restrict__ db,
                          unsigned char* __restrict__ bb){
  __shared__ unsigned char lut8[10][H_];
  int i = blockIdx.x;
  if (threadIdx.x < 80)
    ((unsigned char*)lut8)[threadIdx.x] = f2fp8(db[threadIdx.x] * LOG2E);
  __syncthreads();
  for (int u = threadIdx.x; u < BSTRIDE / 8; u += 256){
    int dp[8];
    #pragma unroll
    for (int k = 0; k < 8; k++){
      int j = u * 8 + k;
      int d = 0;
      if (i > 0 && j > 0 && j < NF){
        int dv = dist[(long)(i - 1) * N_ + (j - 1)];
        d = max(0, min(dv, 9));
      }
      dp[k] = (j < NF) ? d : -1;
    }
    #pragma unroll
    for (int h = 0; h < H_; h++){
      unsigned lo = 0, hi = 0;
      #pragma unroll
      for (int k = 0; k < 4; k++){
        unsigned b0 = (dp[k] >= 0) ? lut8[dp[k]][h] : 0u;
        unsigned b1 = (dp[4 + k] >= 0) ? lut8[dp[4 + k]][h] : 0u;
        lo |= b0 << (8 * k);
        hi |= b1 << (8 * k);
      }
      *(uint2*)(bb + ((long)h * NF + i) * BSTRIDE + u * 8) = make_uint2(lo, hi);
    }
  }
}

// sparse edge-feature bias: byte-CAS fp8 add (also log2e-scaled)
__global__ void edge_bias(const float* __restrict__ ea, const float* __restrict__ W,
                          const float* __restrict__ b, const int* __restrict__ ei,
                          unsigned char* __restrict__ bb){
  int e = blockIdx.x * blockDim.x + threadIdx.x;
  if (e >= E_) return;
  float a[EF_];
  #pragma unroll
  for (int k = 0; k < EF_; k++) a[k] = ea[(long)e * EF_ + k];
  int src = ei[e], dst = ei[E_ + e];
  #pragma unroll
  for (int h = 0; h < H_; h++){
    float p = b[h];
    #pragma unroll
    for (int k = 0; k < EF_; k++) p += a[k] * W[h * EF_ + k];
    atomic_add_fp8(bb + ((long)h * NF + src + 1) * BSTRIDE + (dst + 1), p * LOG2E);
  }
}

// all weight conversions in one dispatch
__global__ void w2b_all(const float* __restrict__ qw, const float* __restrict__ kw,
                        const float* __restrict__ vw, const float* __restrict__ ow,
                        const float* __restrict__ f1w, const float* __restrict__ f2w,
                        short* __restrict__ wqkv, short* __restrict__ owb,
                        short* __restrict__ f1wb, short* __restrict__ f2wb){
  long i = (long)blockIdx.x * 256 + threadIdx.x;
  const long DD = (long)D_ * D_, LDD = (long)L_ * DD, LFD = (long)L_ * FFN_ * D_;
  if (i < LDD){
    long l = i / DD, r = i - l * DD;
    wqkv[l * 3 * DD + r]          = (short)f2b(qw[i]);
    wqkv[l * 3 * DD + DD + r]     = (short)f2b(kw[i]);
    wqkv[l * 3 * DD + 2 * DD + r] = (short)f2b(vw[i]);
    owb[i] = (short)f2b(ow[i]);
  }
  if (i < LFD){
    f1wb[i] = (short)f2b(f1w[i]);
    f2wb[i] = (short)f2b(f2w[i]);
  }
}

// wave-per-row layernorm: 4 rows/block, no LDS, no barriers.
// (R6 post-mortem: fusing LN into GEMM prologues recomputes it 12-16x per
// row tile — regressed 59us. Graph-captured dispatches are cheap.)
__global__ __launch_bounds__(256) void ln_k(const float* __restrict__ in,
                     const float* __restrict__ s, const float* __restrict__ b,
                     float* __restrict__ outf, short* __restrict__ outb,
                     int dup0, int M){
  int row = blockIdx.x * 4 + (threadIdx.x >> 6);
  int lane = threadIdx.x & 63;
  if (row >= M) return;
  float4 v = *(const float4*)(in + (long)row * D_ + lane * 4);
  float s1 = v.x + v.y + v.z + v.w;
  float s2 = v.x * v.x + v.y * v.y + v.z * v.z + v.w * v.w;
  #pragma unroll
  for (int o = 1; o < 64; o <<= 1){
    s1 += __shfl_xor(s1, o, 64);
    s2 += __shfl_xor(s2, o, 64);
  }
  float m = s1 * (1.0f / D_);
  float var = s2 * (1.0f / D_) - m * m;
  float rstd = rsqrtf(var + 1e-5f);
  float4 sc = *(const float4*)(s + lane * 4);
  float4 bb = *(const float4*)(b + lane * 4);
  float y0 = (v.x - m) * rstd * sc.x + bb.x;
  float y1 = (v.y - m) * rstd * sc.y + bb.y;
  float y2 = (v.z - m) * rstd * sc.z + bb.z;
  float y3 = (v.w - m) * rstd * sc.w + bb.w;
  if (outf){
    float4 o4 = make_float4(y0, y1, y2, y3);
    *(float4*)(outf + (long)row * D_ + lane * 4) = o4;
    if (dup0 && row == 0) *(float4*)(outf + (long)NF * D_ + lane * 4) = o4;
  }
  if (outb){
    short4 pk;
    pk.x = (short)f2b(y0); pk.y = (short)f2b(y1);
    pk.z = (short)f2b(y2); pk.w = (short)f2b(y3);
    *(short4*)(outb + (long)row * D_ + lane * 4) = pk;
  }
}

// merge attention partials ONCE per row (was redundantly recomputed by all
// 8 (bn,z) blocks of the O-proj mgemm MERGE path): same q-summation order,
// same 1/L divide, same f2b -> bit-identical A values for the GEMM.
__global__ __launch_bounds__(256) void omerge_k(const float* __restrict__ Op,
    const float* __restrict__ Lp, short* __restrict__ ob){
  int row = blockIdx.x * 4 + (threadIdx.x >> 6);
  int lane = threadIdx.x & 63;
  if (row >= NF) return;
  int hh = lane >> 3;           // head = (lane*4)/32
  int d0 = (lane & 7) * 4;      // dim within head
  float o0 = 0.f, o1 = 0.f, o2 = 0.f, o3 = 0.f, sl = 0.f;
  #pragma unroll
  for (int q = 0; q < NSPLIT; q++){
    long rb = (long)(q * H_ + hh) * RPAD + row;
    float4 v = *(const float4*)(Op + rb * HD_ + d0);
    o0 += v.x; o1 += v.y; o2 += v.z; o3 += v.w;
    sl += Lp[rb];
  }
  float inv = 1.0f / sl;
  short4 pk;
  pk.x = (short)f2b(o0 * inv); pk.y = (short)f2b(o1 * inv);
  pk.z = (short)f2b(o2 * inv); pk.w = (short)f2b(o3 * inv);
  *(short4*)(ob + (long)row * D_ + lane * 4) = pk;
}

// ---- fused QKV MFMA GEMM: grid (33, 4, 3). z==0 (Q) is pre-scaled by
// (1/sqrt(HD))*log2e so fattn's softmax works in the exp2 domain.
// z==2 (V): epilogue transposes the 64x64 tile through LDS so Vtg rows are
// written with coalesced 128B segments.
// Double-buffered LDS: one barrier per K-step, next tile staged before compute.
__global__ __launch_bounds__(256) void qkv_gemm(const short* __restrict__ A,
    const short* __restrict__ Wall, const float* __restrict__ qb,
    const float* __restrict__ kb, const float* __restrict__ vb,
    short* __restrict__ QKb, short* __restrict__ Vtg, int l){
  const int z = blockIdx.z;
  const short* W = Wall + ((long)(l * 3 + z)) * D_ * D_;
  const float* bsp = (z == 0) ? qb : (z == 1) ? kb : vb;
  __shared__ __align__(16) short As[2][64][40], Ws[2][64][40];
  __shared__ __align__(16) short Tt[64][72];   // V transpose buffer [dim][key]
  const int tid = threadIdx.x, lane = tid & 63, wave = tid >> 6;
  const int col = lane & 15, quad = lane >> 4;
  const int wm = wave & 1, wn = wave >> 1;
  const int bm = blockIdx.x * 64, bn = blockIdx.y * 64;
  const f32x4 zero4 = {0.f, 0.f, 0.f, 0.f};
  f32x4 acc[2][2] = {{zero4, zero4}, {zero4, zero4}};
  const int row = tid >> 2, seg = tid & 3;

  auto stage = [&](int buf, int k0){
    bf16x8 av = (bf16x8)(short)0;
    int gm = bm + row;
    if (gm < NF) av = *(const bf16x8*)(A + (long)gm * D_ + k0 + seg * 8);
    *(bf16x8*)&As[buf][row][seg * 8] = av;
    *(bf16x8*)&Ws[buf][row][seg * 8] =
      *(const bf16x8*)(W + (long)(bn + row) * D_ + k0 + seg * 8);
  };

  stage(0, 0);
  int cur = 0;
  for (int k0 = 0; k0 < D_; k0 += 32){
    __syncthreads();
    if (k0 + 32 < D_) stage(cur ^ 1, k0 + 32);
    bf16x8 a0 = *(const bf16x8*)&As[cur][wm * 32 + col][quad * 8];
    bf16x8 a1 = *(const bf16x8*)&As[cur][wm * 32 + 16 + col][quad * 8];
    bf16x8 b0 = *(const bf16x8*)&Ws[cur][wn * 32 + col][quad * 8];
    bf16x8 b1 = *(const bf16x8*)&Ws[cur][wn * 32 + 16 + col][quad * 8];
    acc[0][0] = __builtin_amdgcn_mfma_f32_16x16x32_bf16(a0, b0, acc[0][0], 0, 0, 0);
    acc[0][1] = __builtin_amdgcn_mfma_f32_16x16x32_bf16(a0, b1, acc[0][1], 0, 0, 0);
    acc[1][0] = __builtin_amdgcn_mfma_f32_16x16x32_bf16(a1, b0, acc[1][0], 0, 0, 0);
    acc[1][1] = __builtin_amdgcn_mfma_f32_16x16x32_bf16(a1, b1, acc[1][1], 0, 0, 0);
    cur ^= 1;
  }
  if (z < 2){
    const float qscale = 0.25501133194822025f;  // (1/sqrt(32)) * log2e
    #pragma unroll
    for (int i = 0; i < 2; i++)
      #pragma unroll
      for (int j = 0; j < 2; j++)
        #pragma unroll
        for (int r = 0; r < 4; r++){
          int gm = bm + wm * 32 + i * 16 + quad * 4 + r;
          if (gm >= NF) continue;
          int gn = bn + wn * 32 + j * 16 + col;
          float v = acc[i][j][r] + bsp[gn];
          if (z == 0) v *= qscale;
          QKb[(long)z * NF * D_ + (long)gm * D_ + gn] = (short)f2b(v);
        }
  } else {
    // transpose tile into LDS: Tt[dim][key]; rows gm>=NF hold finite values
    #pragma unroll
    for (int i = 0; i < 2; i++)
      #pragma unroll
      for (int j = 0; j < 2; j++){
        int ln_ = wn * 32 + j * 16 + col;     // local dim
        int lc = wm * 32 + i * 16 + quad * 4; // local key base (4 consecutive)
        float bsv = bsp[bn + ln_];
        short pk[4];
        #pragma unroll
        for (int r = 0; r < 4; r++) pk[r] = (short)f2b(acc[i][j][r] + bsv);
        *(short4*)&Tt[ln_][lc] = *(short4*)pk;
      }
    __syncthreads();
    int lr = tid >> 2, sg = tid & 3;
    bf16x8 v0 = *(const bf16x8*)&Tt[lr][sg * 16];
    bf16x8 v1 = *(const bf16x8*)&Tt[lr][sg * 16 + 8];
    short* dstp = Vtg + (long)(bn + lr) * BSTRIDE + bm + sg * 16;
    *(bf16x8*)dstp = v0;
    *(bf16x8*)(dstp + 8) = v1;
  }
}

// ---- generic MFMA GEMM, double-buffered LDS (one barrier per K-step).
// ATOM=1: atomicAdd partial into Cf (bias added by z==0 block); else bf16 out + ACT.
template<int ACT, int ATOM>
__global__ __launch_bounds__(256) void mgemm(const short* __restrict__ A,
    const short* __restrict__ W, const float* __restrict__ bs,
    float* __restrict__ Cf, short* __restrict__ Cb,
    int M, int Nn, int Kc, int Kstride){
  __shared__ __align__(16) short As[2][64][40], Ws[2][64][40];
  const int tid = threadIdx.x, lane = tid & 63, wave = tid >> 6;
  const int col = lane & 15, quad = lane >> 4;
  const int wm = wave & 1, wn = wave >> 1;
  const int bm = blockIdx.x * 64, bn = blockIdx.y * 64;
  const int koff = blockIdx.z * Kc;
  const f32x4 zero4 = {0.f, 0.f, 0.f, 0.f};
  f32x4 acc[2][2] = {{zero4, zero4}, {zero4, zero4}};
  const int row = tid >> 2, seg = tid & 3;

  auto stage = [&](int buf, int k0){
    int gm = bm + row;
    bf16x8 av = (bf16x8)(short)0;
    if (gm < M) av = *(const bf16x8*)(A + (long)gm * Kstride + koff + k0 + seg * 8);
    *(bf16x8*)&As[buf][row][seg * 8] = av;
    *(bf16x8*)&Ws[buf][row][seg * 8] =
      *(const bf16x8*)(W + (long)(bn + row) * Kstride + koff + k0 + seg * 8);
  };

  stage(0, 0);
  const int nk = Kc >> 5;
  int cur = 0;
  for (int i = 0; i < nk; i++){
    __syncthreads();
    if (i + 1 < nk) stage(cur ^ 1, (i + 1) << 5);
    bf16x8 a0 = *(const bf16x8*)&As[cur][wm * 32 + col][quad * 8];
    bf16x8 a1 = *(const bf16x8*)&As[cur][wm * 32 + 16 + col][quad * 8];
    bf16x8 b0 = *(const bf16x8*)&Ws[cur][wn * 32 + col][quad * 8];
    bf16x8 b1 = *(const bf16x8*)&Ws[cur][wn * 32 + 16 + col][quad * 8];
    acc[0][0] = __builtin_amdgcn_mfma_f32_16x16x32_bf16(a0, b0, acc[0][0], 0, 0, 0);
    acc[0][1] = __builtin_amdgcn_mfma_f32_16x16x32_bf16(a0, b1, acc[0][1], 0, 0, 0);
    acc[1][0] = __builtin_amdgcn_mfma_f32_16x16x32_bf16(a1, b0, acc[1][0], 0, 0, 0);
    acc[1][1] = __builtin_amdgcn_mfma_f32_16x16x32_bf16(a1, b1, acc[1][1], 0, 0, 0);
    cur ^= 1;
  }
  #pragma unroll
  for (int i = 0; i < 2; i++)
    #pragma unroll
    for (int j = 0; j < 2; j++)
      #pragma unroll
      for (int r = 0; r < 4; r++){
        int gm = bm + wm * 32 + i * 16 + quad * 4 + r;
        if (gm >= M) continue;
        int gn = bn + wn * 32 + j * 16 + col;
        if (ATOM){
          float v = acc[i][j][r] + (blockIdx.z == 0 ? bs[gn] : 0.f);
          atomicAdd(&Cf[(long)gm * Nn + gn], v);
        } else {
          float v = acc[i][j][r] + bs[gn];
          if (ACT == 1) v = v * 0.5f * (1.0f + erff(v * 0.70710678118654752f));
          Cb[(long)gm * Nn + gn] = (short)f2b(v);
        }
      }
}

// ---- flash attention, fixed-shift softmax in exp2 domain.
// grid (33, H, NSPLIT); block = 4 waves x 16 rows. (R7 post-mortem: the
// 128-row variant cut staging/barriers per Q-row but the 2x accumulator
// state + 38KB LDS cost occupancy and regressed ~30us; 64-row is optimal.)
// Row-sum of P via an extra MFMA against an all-ones B fragment (bit-exact
// consistency with PV). K/V double-buffered, one barrier per tile.
// NOTE (R3 post-mortem): direct-global K/V fragments regressed 1.7x; LDS
// staging is load-SHARING across waves; keep it.
__global__ __launch_bounds__(256) void fattn_k(const short* __restrict__ Qb,
    const short* __restrict__ Kb, const short* __restrict__ Vtg,
    const unsigned char* __restrict__ bias8, float* __restrict__ Opart,
    float* __restrict__ Lpart){
  __shared__ __align__(16) short Ks[2][64][42];  // stride 42: 2-way max on permuted reads
  __shared__ __align__(16) short Vt[2][32][72];
  __shared__ __align__(16) short Ps[4][16][72];

  const int tid = threadIdx.x, wave = tid >> 6, lane = tid & 63;
  const int col = lane & 15, quad = lane >> 4;
  const int h = blockIdx.y, qz = blockIdx.z;
  const int i0 = blockIdx.x * 64 + wave * 16;
  const int t0 = (qz == 0) ? 0 : 9 + 8 * (qz - 1);   // 0,9,17,25
  const int t1 = t0 + ((qz == 0) ? 9 : 8);           // 33 tiles total

  int qrow = min(i0 + col, NF - 1);
  bf16x8 qf = *(const bf16x8*)(Qb + (long)qrow * D_ + h * HD_ + quad * 8);

  int brow[4];
  #pragma unroll
  for (int r = 0; r < 4; r++) brow[r] = min(i0 + quad * 4 + r, NF - 1);

  f32x4 oacc0 = {0.f, 0.f, 0.f, 0.f}, oacc1 = {0.f, 0.f, 0.f, 0.f};
  f32x4 racc = {0.f, 0.f, 0.f, 0.f};
  const f32x4 zero4 = {0.f, 0.f, 0.f, 0.f};
  const bf16x8 ones8 = (bf16x8)(short)0x3F80;   // bf16 1.0 splat
  short* Pp = &Ps[wave][0][0];

  auto stageKV = [&](int buf, int t){
    int j0 = t * 64;
    { // K tile: 64 keys x 32 dims
      int key = tid >> 2, seg = tid & 3;
      int j = j0 + key;
      bf16x8 kv = (bf16x8)(short)0;
      if (j < NF) kv = *(const bf16x8*)(Kb + (long)j * D_ + h * HD_ + seg * 8);
      *(bf16x8*)&Ks[buf][key][seg * 8] = kv;
    }
    { // V tile (pre-transposed): 32 dims x 64 keys
      int d = tid >> 3, seg = tid & 7;
      *(bf16x8*)&Vt[buf][d][seg * 8] =
        *(const bf16x8*)(Vtg + (long)(h * HD_ + d) * BSTRIDE + j0 + seg * 8);
    }
  };

  stageKV(0, t0);
  int cur = 0;
  for (int t = t0; t < t1; t++){
    const int j0 = t * 64;
    // bias: one dword per row (4 fp8 bytes for t4=0..3), coalesced across col
    unsigned bw[4];
    #pragma unroll
    for (int r = 0; r < 4; r++)
      bw[r] = *(const unsigned*)(bias8 + (long)(h * NF + brow[r]) * BSTRIDE + j0 + col * 4);
    __syncthreads();
    if (t + 1 < t1) stageKV(cur ^ 1, t + 1);

    f32x4 sacc[4];
    #pragma unroll
    for (int t4 = 0; t4 < 4; t4++){
      bf16x8 kf = *(const bf16x8*)&Ks[cur][col * 4 + t4][quad * 8];
      sacc[t4] = __builtin_amdgcn_mfma_f32_16x16x32_bf16(qf, kf, zero4, 0, 0, 0);
    }

    if (j0 + 64 > NF){
      // masked tail tile (only t==32, qz==3)
      #pragma unroll
      for (int r = 0; r < 4; r++){
        unsigned w = bw[r];
        float s0 = sacc[0][r] + __builtin_amdgcn_cvt_f32_fp8((int)w, 0);
        float s1 = sacc[1][r] + __builtin_amdgcn_cvt_f32_fp8((int)w, 1);
        float s2 = sacc[2][r] + __builtin_amdgcn_cvt_f32_fp8((int)w, 2);
        float s3 = sacc[3][r] + __builtin_amdgcn_cvt_f32_fp8((int)w, 3);
        unsigned p0 = (j0 + col * 4 + 0 < NF) ? __float_as_uint(exp2f(s0)) : 0u;
        unsigned p1 = (j0 + col * 4 + 1 < NF) ? __float_as_uint(exp2f(s1)) : 0u;
        unsigned p2 = (j0 + col * 4 + 2 < NF) ? __float_as_uint(exp2f(s2)) : 0u;
        unsigned p3 = (j0 + col * 4 + 3 < NF) ? __float_as_uint(exp2f(s3)) : 0u;
        unsigned u0 = (p0 >> 16) | (p1 & 0xffff0000u);
        unsigned u1 = (p2 >> 16) | (p3 & 0xffff0000u);
        *(uint2*)&Pp[(quad * 4 + r) * 72 + col * 4] = make_uint2(u0, u1);
      }
    } else {
      #pragma unroll
      for (int r = 0; r < 4; r++){
        unsigned w = bw[r];
        float s0 = sacc[0][r] + __builtin_amdgcn_cvt_f32_fp8((int)w, 0);
        float s1 = sacc[1][r] + __builtin_amdgcn_cvt_f32_fp8((int)w, 1);
        float s2 = sacc[2][r] + __builtin_amdgcn_cvt_f32_fp8((int)w, 2);
        float s3 = sacc[3][r] + __builtin_amdgcn_cvt_f32_fp8((int)w, 3);
        unsigned p0 = __float_as_uint(exp2f(s0));
        unsigned p1 = __float_as_uint(exp2f(s1));
        unsigned p2 = __float_as_uint(exp2f(s2));
        unsigned p3 = __float_as_uint(exp2f(s3));
        unsigned u0 = (p0 >> 16) | (p1 & 0xffff0000u);
        unsigned u1 = (p2 >> 16) | (p3 & 0xffff0000u);
        *(uint2*)&Pp[(quad * 4 + r) * 72 + col * 4] = make_uint2(u0, u1);
      }
    }

    #pragma unroll
    for (int ks = 0; ks < 2; ks++){
      bf16x8 af = *(const bf16x8*)&Pp[col * 72 + ks * 32 + quad * 8];
      bf16x8 v0 = *(const bf16x8*)&Vt[cur][col][ks * 32 + quad * 8];
      bf16x8 v1 = *(const bf16x8*)&Vt[cur][16 + col][ks * 32 + quad * 8];
      oacc0 = __builtin_amdgcn_mfma_f32_16x16x32_bf16(af, v0, oacc0, 0, 0, 0);
      oacc1 = __builtin_amdgcn_mfma_f32_16x16x32_bf16(af, v1, oacc1, 0, 0, 0);
      racc  = __builtin_amdgcn_mfma_f32_16x16x32_bf16(af, ones8, racc, 0, 0, 0);
    }
    cur ^= 1;
  }

  long pi = ((long)qz * H_ + h) * RPAD + i0 + quad * 4;
  #pragma unroll
  for (int r = 0; r < 4; r++){
    Opart[(pi + r) * HD_ + col] = oacc0[r];
    Opart[(pi + r) * HD_ + 16 + col] = oacc1[r];
    if (col == 0) Lpart[pi + r] = racc[r];
  }
}

extern "C" void kernel_launch(void* const* d_in, const int* in_sizes, int n_in,
                              void* d_out, int out_size, void* d_ws, size_t ws_size,
                              hipStream_t stream){
  const float* x    = (const float*)d_in[0];
  const float* ea   = (const float*)d_in[1];
  const float* npw  = (const float*)d_in[2];
  const float* npb  = (const float*)d_in[3];
  const float* inE  = (const float*)d_in[4];
  const float* outE = (const float*)d_in[5];
  const float* db   = (const float*)d_in[6];
  const float* epw  = (const float*)d_in[7];
  const float* epb  = (const float*)d_in[8];
  const float* cls  = (const float*)d_in[9];
  const float* qw   = (const float*)d_in[10];
  const float* qb   = (const float*)d_in[11];
  const float* kw   = (const float*)d_in[12];
  const float* kb   = (const float*)d_in[13];
  const float* vw   = (const float*)d_in[14];
  const float* vb   = (const float*)d_in[15];
  const float* ow   = (const float*)d_in[16];
  const float* ob   = (const float*)d_in[17];
  const float* f1w  = (const float*)d_in[18];
  const float* f1b  = (const float*)d_in[19];
  const float* f2w  = (const float*)d_in[20];
  const float* f2bp = (const float*)d_in[21];
  const float* ln1s = (const float*)d_in[22];
  const float* ln1b = (const float*)d_in[23];
  const float* ln2s = (const float*)d_in[24];
  const float* ln2b = (const float*)d_in[25];
  const float* fns  = (const float*)d_in[26];
  const float* fnb  = (const float*)d_in[27];
  const int*   ei   = (const int*)d_in[28];
  const int*   dist = (const int*)d_in[29];

  float* ws = (float*)d_ws;
  long off = 0;
  float* h     = ws + off; off += (long)NF * D_;
  float* Opart = ws + off; off += (long)NSPLIT * H_ * RPAD * HD_;
  float* Lpart = ws + off; off += (long)NSPLIT * H_ * RPAD;
  unsigned char* bias8 = (unsigned char*)(ws + off);
  off += ((long)H_ * NF * BSTRIDE + 3) / 4;
  short* hnb   = (short*)(ws + off); off += ((long)NF * D_ + 1) / 2;
  short* obuf  = (short*)(ws + off); off += ((long)NF * D_ + 1) / 2;
  short* QKb   = (short*)(ws + off); off += (long)NF * D_;      // Q then K
  short* Vtg   = (short*)(ws + off); off += ((long)D_ * BSTRIDE + 1) / 2;
  short* midb  = (short*)(ws + off); off += ((long)NF * FFN_ + 1) / 2;
  short* wqkv  = (short*)(ws + off); off += ((long)3 * L_ * D_ * D_ + 1) / 2;
  short* owb   = (short*)(ws + off); off += ((long)L_ * D_ * D_ + 1) / 2;
  short* f1wb  = (short*)(ws + off); off += ((long)L_ * FFN_ * D_ + 1) / 2;
  short* f2wb  = (short*)(ws + off); off += ((long)L_ * FFN_ * D_ + 1) / 2;
  int*   ind   = (int*)(ws + off);
  int*   outd  = ind + N_;

  zero_int<<<(2 * N_ + 255) / 256, 256, 0, stream>>>(ind, 2 * N_);
  deg_count<<<(E_ + 255) / 256, 256, 0, stream>>>(ei, ind, outd);
  embed_k<<<NF, D_, 0, stream>>>(x, npw, npb, inE, outE, ind, outd, cls, h);
  bias_fill<<<NF, 256, 0, stream>>>(dist, db, bias8);
  edge_bias<<<(E_ + 255) / 256, 256, 0, stream>>>(ea, epw, epb, ei, bias8);
  {
    long LFD = (long)L_ * FFN_ * D_;
    w2b_all<<<(int)((LFD + 255) / 256), 256, 0, stream>>>(qw, kw, vw, ow, f1w, f2w,
                                                          wqkv, owb, f1wb, f2wb);
  }

  const int gLN = (NF + 3) / 4;
  dim3 gQKV((NF + 63) / 64, D_ / 64, 3);
  dim3 gO((NF + 63) / 64, D_ / 64, 2);
  dim3 gF((NF + 63) / 64, FFN_ / 64, 1);
  dim3 gF2((NF + 63) / 64, D_ / 64, 4);
  dim3 gA((NF + 63) / 64, H_, NSPLIT);
  for (int l = 0; l < L_; l++){
    ln_k<<<gLN, 256, 0, stream>>>(h, ln1s + l * D_, ln1b + l * D_, nullptr, hnb, 0, NF);
    qkv_gemm<<<gQKV, 256, 0, stream>>>(hnb, wqkv, qb + l * D_, kb + l * D_, vb + l * D_,
                                       QKb, Vtg, l);
    fattn_k<<<gA, 256, 0, stream>>>(QKb, QKb + (long)NF * D_, Vtg, bias8, Opart, Lpart);
    omerge_k<<<gLN, 256, 0, stream>>>(Opart, Lpart, obuf);
    mgemm<0,1><<<gO, 256, 0, stream>>>(obuf, owb + (long)l * D_ * D_, ob + l * D_,
                                       h, nullptr, NF, D_, 128, D_);
    ln_k<<<gLN, 256, 0, stream>>>(h, ln2s + l * D_, ln2b + l * D_, nullptr, hnb, 0, NF);
    mgemm<1,0><<<gF, 256, 0, stream>>>(hnb, f1wb + (long)l * FFN_ * D_, f1b + l * FFN_,
                                       nullptr, midb, NF, FFN_, D_, D_);
    mgemm<0,1><<<gF2, 256, 0, stream>>>(midb, f2wb + (long)l * FFN_ * D_, f2bp + l * D_,
                                        h, nullptr, NF, D_, 256, FFN_);
  }
  ln_k<<<gLN, 256, 0, stream>>>(h, fns, fnb, (float*)d_out, nullptr, 1, NF);
}